// Round 7
// baseline (3844.815 us; speedup 1.0000x reference)
//
#include <hip/hip_runtime.h>
#include <hip/hip_bf16.h>
#include <math.h>

#define L_LOC 12769              // 113*113 sliding-window positions
#define NB 2
#define NLR (NB * L_LOC)
#define NW 20

typedef short short8v __attribute__((ext_vector_type(8)));
typedef float f32x4 __attribute__((ext_vector_type(4)));
typedef __hip_bfloat16 bf16;

__device__ __forceinline__ float softf(float x, float l) {
  float a = fmaxf(fabsf(x) - l, 0.0f);
  return x > 0.0f ? a : (x < 0.0f ? -a : 0.0f);
}
__device__ __forceinline__ float sigf(float x) { return 1.0f / (1.0f + expf(-x)); }
__device__ __forceinline__ void split2(float v, bf16& h, bf16& l) {
  h = __float2bfloat16(v);
  l = __float2bfloat16(v - __bfloat162float(h));
}

// ================= split-bf16 MFMA GEMM ========================================
// A: hi plane at A, lo at A+aOff. B per batch (B0/B1 by m0>=bRow), lo at +bOff.
// TERMS=3: Ah*Bh + Ah*Bl + Al*Bh.  TERMS=2: Ah*(Bh+Bl).  TERMS=1: Ah*Bh.
enum { ME_RELU = 0, ME_SCALE = 1, ME_SIG = 2, ME_Y = 3, ME_SOFT = 4, ME_XP = 5,
       ME_SMAT = 6, ME_LIN = 7 };

template <int EPI, int TERMS, int WLO>
__global__ __launch_bounds__(256) void mgemm_k(
    const bf16* __restrict__ A, int lda, size_t aOff,
    const bf16* __restrict__ B0, const bf16* __restrict__ B1, int ldb, size_t bOff,
    void* __restrict__ Cv, int ldc, size_t cOff,
    bf16* __restrict__ Zp,
    const float* __restrict__ bias,
    const float* __restrict__ E1, const float* __restrict__ E2, int lde,
    const float* __restrict__ cptr, int bRow, int Rc, int r0, int N, int K)
{
  const int NPA = (TERMS >= 3) ? 2 : 1;
  const int NPB = (TERMS >= 2) ? 2 : 1;
  __shared__ char As[(TERMS >= 3) ? 2 : 1][8192];   // [pl][128 rows][32 k] bf16
  __shared__ char Bs[(TERMS >= 2) ? 2 : 1][8192];
  const int t = threadIdx.x;
  const int lane = t & 63, wv = t >> 6;
  const int wr = wv >> 1, wc = wv & 1;
  const int m0 = blockIdx.x * 128, n0 = blockIdx.y * 128;
  const int nb = (m0 >= bRow) ? 1 : 0;
  const bf16* __restrict__ Bt = nb ? B1 : B0;
  const int row16 = lane & 15, kg = lane >> 4;
  const int grow = t >> 2;
  const int gcol = (t & 3) * 8;
  f32x4 acc[4][4];
#pragma unroll
  for (int i = 0; i < 4; ++i)
#pragma unroll
    for (int j = 0; j < 4; ++j) { acc[i][j][0] = 0.f; acc[i][j][1] = 0.f; acc[i][j][2] = 0.f; acc[i][j][3] = 0.f; }

  for (int k0 = 0; k0 < K; k0 += 32) {
#pragma unroll
    for (int h = 0; h < NPA; ++h)
#pragma unroll
      for (int i = 0; i < 2; ++i) {
        const bf16* ga = A + h * aOff + (size_t)(m0 + i * 64 + grow) * lda + k0 + gcol;
        __builtin_amdgcn_global_load_lds(
            (const __attribute__((address_space(1))) void*)ga,
            (__attribute__((address_space(3))) void*)(As[h] + i * 4096 + wv * 1024), 16, 0, 0);
      }
#pragma unroll
    for (int h = 0; h < NPB; ++h)
#pragma unroll
      for (int i = 0; i < 2; ++i) {
        const bf16* gb = Bt + h * bOff + (size_t)(n0 + i * 64 + grow) * ldb + k0 + gcol;
        __builtin_amdgcn_global_load_lds(
            (const __attribute__((address_space(1))) void*)gb,
            (__attribute__((address_space(3))) void*)(Bs[h] + i * 4096 + wv * 1024), 16, 0, 0);
      }
    __syncthreads();
    short8v ah[4], al[4], bh[4], bl[4];
#pragma unroll
    for (int mi = 0; mi < 4; ++mi) {
      int o = (wr * 64 + mi * 16 + row16) * 64 + kg * 16;
      ah[mi] = *(const short8v*)(As[0] + o);
      if (TERMS >= 3) al[mi] = *(const short8v*)(As[NPA - 1] + o);
    }
#pragma unroll
    for (int ni = 0; ni < 4; ++ni) {
      int o = (wc * 64 + ni * 16 + row16) * 64 + kg * 16;
      bh[ni] = *(const short8v*)(Bs[0] + o);
      if (TERMS >= 2) bl[ni] = *(const short8v*)(Bs[NPB - 1] + o);
    }
#pragma unroll
    for (int mi = 0; mi < 4; ++mi)
#pragma unroll
      for (int ni = 0; ni < 4; ++ni) {
        if (TERMS >= 2)
          acc[mi][ni] = __builtin_amdgcn_mfma_f32_16x16x32_bf16(ah[mi], bl[ni], acc[mi][ni], 0, 0, 0);
        if (TERMS >= 3)
          acc[mi][ni] = __builtin_amdgcn_mfma_f32_16x16x32_bf16(al[mi], bh[ni], acc[mi][ni], 0, 0, 0);
        acc[mi][ni] = __builtin_amdgcn_mfma_f32_16x16x32_bf16(ah[mi], bh[ni], acc[mi][ni], 0, 0, 0);
      }
    __syncthreads();
  }

  float invc = 1.0f;
  if (EPI == ME_SCALE || EPI == ME_SOFT || EPI == ME_SMAT) invc = 1.0f / cptr[0];
  bf16* Cb = (bf16*)Cv;
  float* Cf = (float*)Cv;
#pragma unroll
  for (int ni = 0; ni < 4; ++ni) {
    int col = n0 + wc * 64 + ni * 16 + row16;
    const bool colok = col < N;
    float bv = 0.0f;
    if ((EPI == ME_RELU || EPI == ME_SCALE || EPI == ME_SIG || EPI == ME_LIN) && colok)
      bv = bias[col];
#pragma unroll
    for (int mi = 0; mi < 4; ++mi) {
      int rowb = m0 + wr * 64 + mi * 16 + kg * 4;
#pragma unroll
      for (int r = 0; r < 4; ++r) {
        int row = rowb + r;
        float v = acc[mi][ni][r];
        if (EPI == ME_RELU) {
          if (colok) {
            float o = fmaxf(v + bv, 0.0f);
            size_t ci = (size_t)row * ldc + col;
            if (WLO) {
              bf16 h, l; split2(o, h, l);
              Cb[ci] = h; Cb[ci + cOff] = l;
            } else {
              Cb[ci] = __float2bfloat16(o);
            }
          }
        } else if (EPI == ME_LIN) {
          if (colok && row < Rc) Cf[(size_t)row * ldc + col] = v + bv;
        } else if (EPI == ME_SCALE) {
          if (colok) Cf[(size_t)row * ldc + col] = (v + bv) * invc;
        } else if (EPI == ME_SIG) {
          if (colok) {
            int rl = row - nb * bRow;
            if (rl < Rc && rl >= 0)
              Cf[(size_t)col * NLR + (size_t)nb * L_LOC + r0 + rl] = sigf(v + bv);
          }
        } else if (EPI == ME_Y) {
          if (colok) {
            size_t e = (size_t)row * lde + col;
            Cf[(size_t)row * ldc + col] = v;
            Zp[(size_t)row * 640 + col] = __float2bfloat16(softf(v, E1[e]));
          }
        } else if (EPI == ME_SOFT) {
          if (colok) {
            size_t e = (size_t)row * lde + col;
            Cb[(size_t)row * ldc + col] = __float2bfloat16(softf(v + E1[e] * invc, E2[e]));
          }
        } else if (EPI == ME_XP) {
          int rl = row - nb * bRow;
          if (colok && rl < Rc && rl >= 0) {
            size_t g = (size_t)col * NLR + (size_t)nb * L_LOC + r0 + rl;
            Cf[g] = fminf(fmaxf(v, 0.0f), 1.0f) * E1[g];
          }
        } else { // ME_SMAT: write split S directly, zero pads
          float o = (row < 624 && col < 624) ? ((row == col ? 1.0f : 0.0f) - v * invc) : 0.0f;
          bf16 h, l; split2(o, h, l);
          size_t ci = (size_t)row * ldc + col;
          Cb[ci] = h; Cb[ci + cOff] = l;
        }
      }
    }
  }
}

static void mgemm(hipStream_t st, int EPI, int terms, int wlo,
                  const bf16* A, int lda, size_t aOff,
                  const bf16* B0, const bf16* B1, int ldb, size_t bOff,
                  void* C, int ldc, size_t cOff,
                  bf16* Zp,
                  const float* bias, const float* E1, const float* E2, int lde,
                  const float* cptr, int bRow, int Rc, int r0,
                  int Mp, int N, int K)
{
  dim3 grid(Mp / 128, (N + 127) / 128), blk(256);
#define MG(ep, tm, wl) mgemm_k<ep, tm, wl><<<grid, blk, 0, st>>>(A, lda, aOff, B0, B1, ldb, bOff, C, ldc, cOff, Zp, bias, E1, E2, lde, cptr, bRow, Rc, r0, N, K)
  if (EPI == ME_RELU && terms == 1 && !wlo) { MG(ME_RELU, 1, 0); }
  else if (EPI == ME_RELU && terms == 1)    { MG(ME_RELU, 1, 1); }
  else if (EPI == ME_RELU)                  { MG(ME_RELU, 3, 1); }
  else if (EPI == ME_LIN)                   { MG(ME_LIN, 3, 0); }
  else if (EPI == ME_SCALE)                 { MG(ME_SCALE, 3, 0); }
  else if (EPI == ME_SIG)                   { MG(ME_SIG, 1, 0); }
  else if (EPI == ME_Y)                     { MG(ME_Y, 3, 0); }
  else if (EPI == ME_SOFT)                  { MG(ME_SOFT, 2, 0); }
  else if (EPI == ME_XP)                    { MG(ME_XP, 2, 0); }
  else                                      { MG(ME_SMAT, 3, 0); }
#undef MG
}

// ================= small kernels ==============================================
struct WTable {
  const float* src[NW];
  bf16* dst[NW];
  int K[NW], N[NW], Kp[NW], Np[NW];
  long long loOff[NW];
  int base[NW + 1];
};

__global__ void wtransall_k(WTable w) {
  int idx = blockIdx.x * 256 + threadIdx.x;
  if (idx >= w.base[NW]) return;
  int s = 0;
  while (s < NW - 1 && idx >= w.base[s + 1]) ++s;
  int li = idx - w.base[s];
  int Kp = w.Kp[s];
  int n = li / Kp, k = li - n * Kp;
  float v = (n < w.N[s] && k < w.K[s]) ? w.src[s][(size_t)k * w.N[s] + n] : 0.0f;
  bf16 h, l; split2(v, h, l);
  w.dst[s][li] = h;
  w.dst[s][li + w.loOff[s]] = l;
}

__global__ void biascat_k(const float* p1, const float* a1, const float* w1b,
                          const float* q1, const float* b1,
                          float* c1, float* c2) {
  int i = blockIdx.x * 256 + threadIdx.x;
  if (i >= 3072) return;
  int br = i >> 10, o = i & 1023;
  c1[i] = br == 0 ? p1[o] : (br == 1 ? a1[o] : w1b[o]);
  c2[i] = br == 0 ? q1[o] : (br == 1 ? b1[o] : w1b[o]);
}

// ext rows (stride-8 unfold) -> split bf16 [2pl][256 rows][256], pad rows zero
__global__ void extb_k(const float* __restrict__ img, bf16* __restrict__ dst) {
  int idx = blockIdx.x * 256 + threadIdx.x;   // 256*256
  int row = idx >> 8, p = idx & 255;
  float v = 0.0f;
  if (row < 224) {
    int n = row / 112, e = row - n * 112;
    int l1 = 2 * e, i1 = l1 / 15, j1 = l1 - i1 * 15;
    v = img[n * 16384 + (8 * i1 + (p >> 4)) * 128 + 8 * j1 + (p & 15)];
  }
  bf16 h, l; split2(v, h, l);
  dst[idx] = h; dst[idx + 65536] = l;
}

__global__ void rownorm224_k(float* sd) {
  int r = blockIdx.x, t = threadIdx.x;   // 224 blocks x 64 threads
  float v[4], s = 0.0f;
#pragma unroll
  for (int j = 0; j < 4; ++j) { v[j] = sd[r * 256 + t + 64 * j]; s += v[j] * v[j]; }
#pragma unroll
  for (int o = 1; o < 64; o <<= 1) s += __shfl_xor(s, o);
  float sc = 1.0f / fmaxf(sqrtf(s), 1e-12f);
#pragma unroll
  for (int j = 0; j < 4; ++j) sd[r * 256 + t + 64 * j] = v[j] * sc;
}

// Dict [256][512] + Dcat_f sd-part -> Db [n][2pl][256][640], DbT [n][2pl][640][256]
__global__ void dcatconv_k(const float* __restrict__ Dict, const float* __restrict__ Dc,
                           bf16* __restrict__ Db, bf16* __restrict__ DbT) {
  int idx = blockIdx.x * 256 + threadIdx.x;   // 2*256*640
  if (idx >= 327680) return;
  int n = idx / 163840, r = idx - n * 163840;
  int p = r / 640, a = r - p * 640;
  float v = 0.0f;
  if (a < 512)      v = Dict[p * 512 + a];
  else if (a < 624) v = Dc[(size_t)n * 159744 + p * 624 + a];
  bf16 h, l; split2(v, h, l);
  size_t base = (size_t)n * 327680;
  Db[base + p * 640 + a] = h;
  Db[base + 163840 + p * 640 + a] = l;
  DbT[base + (size_t)a * 256 + p] = h;
  DbT[base + 163840 + (size_t)a * 256 + p] = l;
}

// unfold for both batches into the stacked chunk buffer
__global__ void unfold_k(const float* __restrict__ img, bf16* __restrict__ uf,
                         int r0, int Rc, int bRowc, size_t pOff) {
  int bi = blockIdx.x;               // 0..2*Rc-1
  int nb = bi >= Rc;
  int rl = nb ? bi - Rc : bi;
  int row = nb * bRowc + rl;
  int p = threadIdx.x;
  int l = r0 + rl;
  int i0 = l / 113, j0 = l - i0 * 113;
  float v = img[nb * 16384 + (i0 + (p >> 4)) * 128 + j0 + (p & 15)];
  bf16 h, lo; split2(v, h, lo);
  size_t o = (size_t)row * 256 + p;
  uf[o] = h; uf[o + pOff] = lo;
}

// fused CBAM
__global__ __launch_bounds__(1024) void cbam_k(
    const float* __restrict__ sd, const float* __restrict__ w1,
    const float* __restrict__ w2, const float* __restrict__ saw,
    float* __restrict__ Dcat)
{
  __shared__ float mv[512], xv[512], hm[1024], hx[1024], ca[512];
  __shared__ float smean[224], smax[224];
  const int t = threadIdx.x;
  if (t < 512) {
    int n = t >> 8, ch = t & 255;
    float s = 0.0f, m = -INFINITY;
    for (int e = 0; e < 112; ++e) {
      float v = sd[(n * 112 + e) * 256 + ch];
      s += v; m = fmaxf(m, v);
    }
    mv[t] = s * (1.0f / 112.0f);
    xv[t] = m;
  }
  __syncthreads();
  {
    int n = t >> 9, o = t & 511;
    float sm = 0.0f, sx = 0.0f;
    for (int i = 0; i < 256; ++i) {
      float w = w1[i * 512 + o];
      sm += mv[n * 256 + i] * w;
      sx += xv[n * 256 + i] * w;
    }
    hm[t] = fmaxf(sm, 0.0f);
    hx[t] = fmaxf(sx, 0.0f);
  }
  __syncthreads();
  if (t < 512) {
    int n = t >> 8, ch = t & 255;
    float s = 0.0f;
    for (int o = 0; o < 512; ++o) s += (hm[n * 512 + o] + hx[n * 512 + o]) * w2[o * 256 + ch];
    ca[t] = sigf(s);
  }
  __syncthreads();
  if (t < 224) {
    int n = t / 112, s = t % 112;
    float sum = 0.0f, mx = -INFINITY;
    for (int ch = 0; ch < 256; ++ch) {
      float v = sd[(n * 112 + s) * 256 + ch] * ca[n * 256 + ch];
      Dcat[(size_t)n * 159744 + ch * 624 + 512 + s] = v;
      sum += v; mx = fmaxf(mx, v);
    }
    smean[t] = sum * (1.0f / 256.0f);
    smax[t] = mx;
  }
  __syncthreads();
  if (t < 224) {
    int n = t / 112, s = t % 112;
    int h = s / 14, w = s % 14;
    float acc = 0.0f;
    for (int dh = 0; dh < 7; ++dh) {
      int hh = h + dh - 3; if (hh < 0 || hh >= 8) continue;
      for (int dw = 0; dw < 7; ++dw) {
        int ww = w + dw - 3; if (ww < 0 || ww >= 14) continue;
        int sp = hh * 14 + ww;
        acc += smean[n * 112 + sp] * saw[dh * 7 + dw] + smax[n * 112 + sp] * saw[49 + dh * 7 + dw];
      }
    }
    float sg = sigf(acc);
    for (int ch = 0; ch < 256; ++ch) Dcat[(size_t)n * 159744 + ch * 624 + 512 + s] *= sg;
  }
}

// overlap-add fold + divide; xpT/wgT are [256 patch][NLR row] (coalesced reads)
__global__ void folddiv_k(const float* __restrict__ xpT, const float* __restrict__ wgT,
                          float* __restrict__ out) {
  int idx = blockIdx.x * 256 + threadIdx.x;
  if (idx >= 32768) return;
  int n = idx >> 14, rem = idx & 16383;
  int i = rem >> 7, j = rem & 127;
  float num = 0.0f, den = 0.0f;
  int kh0 = (i - 112 > 0) ? i - 112 : 0;
  int kh1 = (i < 15) ? i : 15;
  int kw0 = (j - 112 > 0) ? j - 112 : 0;
  int kw1 = (j < 15) ? j : 15;
  for (int kh = kh0; kh <= kh1; ++kh)
    for (int kw = kw0; kw <= kw1; ++kw) {
      int l = (i - kh) * 113 + (j - kw);
      size_t base = (size_t)(kh * 16 + kw) * NLR + (size_t)n * L_LOC + l;
      num += xpT[base];
      den += wgT[base];
    }
  out[idx] = num / den;
}

// ================= host orchestration ==========================================
struct Bufs {
  float *xp, *wg, *Dcat_f, *sd, *res;
  bf16 *Db, *DbT, *Sb;
  bf16 *extb, *sdh1, *sdh2, *sdh3;
  bf16 *uf, *h1, *h2, *z, *zn;
  float *thr, *y;
  size_t ufO, h2O;
  int R;
};

static void run_stage(hipStream_t st, const float* const* in, const float* img,
                      float* outimg, int pd0, int lam0,
                      const bf16* Wcat, const float* bcat,
                      bf16* const* WtPd, bf16* const* WtLam, bf16* const* WtW,
                      bf16* const* Ws, const Bufs& b)
{
  const float* cptr = in[2];
  const int BIG = 1 << 30;
  // --- adaptive dictionary pipeline via MFMA (TERMS=3 ~ fp32) ---
  extb_k<<<dim3(256), dim3(256), 0, st>>>(img, b.extb);
  mgemm(st, ME_RELU, 3, 1, b.extb, 256, 65536, Ws[0], Ws[0], 256, 512 * 256,
        b.sdh1, 512, 256 * 512, 0, in[4], 0, 0, 0, cptr, BIG, 224, 0, 256, 512, 256);
  mgemm(st, ME_RELU, 3, 1, b.sdh1, 512, 256 * 512, Ws[1], Ws[1], 512, 1024 * 512,
        b.sdh2, 1024, 256 * 1024, 0, in[6], 0, 0, 0, cptr, BIG, 224, 0, 256, 1024, 512);
  mgemm(st, ME_RELU, 3, 1, b.sdh2, 1024, 256 * 1024, Ws[2], Ws[2], 1024, 512 * 1024,
        b.sdh3, 512, 256 * 512, 0, in[8], 0, 0, 0, cptr, BIG, 224, 0, 256, 512, 1024);
  mgemm(st, ME_LIN, 3, 0, b.sdh3, 512, 256 * 512, Ws[3], Ws[3], 512, 256 * 512,
        b.sd, 256, 0, 0, in[10], 0, 0, 0, cptr, BIG, 224, 0, 256, 256, 512);
  rownorm224_k<<<dim3(224), dim3(64), 0, st>>>(b.sd);
  cbam_k<<<dim3(1), dim3(1024), 0, st>>>(b.sd, in[41], in[42], in[43], b.Dcat_f);
  dcatconv_k<<<dim3(1280), dim3(256), 0, st>>>(in[1], b.Dcat_f, b.Db, b.DbT);
  // --- S = I - D^T D / c via split MFMA, fused split-bf16 output ---
  for (int n = 0; n < NB; ++n) {
    const bf16* Dt = b.DbT + (size_t)n * 327680;
    mgemm(st, ME_SMAT, 3, 0, Dt, 256, 163840, Dt, Dt, 256, 163840,
          b.Sb + (size_t)n * 819200, 640, 409600, 0,
          0, 0, 0, 0, cptr, BIG, 624, 0, 640, 640, 256);
  }

  // --- stacked both-batch chunks ---
  for (int r0 = 0; r0 < L_LOC; r0 += b.R) {
    int Rc = L_LOC - r0; if (Rc > b.R) Rc = b.R;
    int bRowc = ((Rc + 127) / 128) * 128;
    int Mp = 2 * bRowc;
    unfold_k<<<dim3(2 * Rc), dim3(256), 0, st>>>(img, b.uf, r0, Rc, bRowc, b.ufO);
    // merged L1 (pd | lam | w) -> h1all [rows][3072]
    mgemm(st, ME_RELU, 1, 0, b.uf, 256, b.ufO, Wcat, Wcat, 256, 3072 * 256,
          b.h1, 3072, 0, 0, bcat, 0, 0, 0, cptr, bRowc, Rc, r0, Mp, 3072, 256);
    // pd L2, L3 -> thr[:, :512]
    mgemm(st, ME_RELU, 1, 1, b.h1, 3072, 0, WtPd[1], WtPd[1], 1024, 512 * 1024,
          b.h2, 512, b.h2O, 0, in[pd0 + 3], 0, 0, 0, cptr, bRowc, Rc, r0, Mp, 512, 1024);
    mgemm(st, ME_SCALE, 3, 0, b.h2, 512, b.h2O, WtPd[2], WtPd[2], 512, 512 * 512,
          b.thr, 640, 0, 0, in[pd0 + 5], 0, 0, 0, cptr, bRowc, Rc, r0, Mp, 512, 512);
    // lam L2, L3 -> thr[:, 512:624]
    mgemm(st, ME_RELU, 1, 1, b.h1 + 1024, 3072, 0, WtLam[1], WtLam[1], 1024, 512 * 1024,
          b.h2, 512, b.h2O, 0, in[lam0 + 3], 0, 0, 0, cptr, bRowc, Rc, r0, Mp, 512, 1024);
    mgemm(st, ME_SCALE, 3, 0, b.h2, 512, b.h2O, WtLam[2], WtLam[2], 512, 128 * 512,
          b.thr + 512, 640, 0, 0, in[lam0 + 5], 0, 0, 0, cptr, bRowc, Rc, r0, Mp, 112, 512);
    // w L2, L3 -> WgT (transposed, sigmoid)
    mgemm(st, ME_RELU, 1, 1, b.h1 + 2048, 3072, 0, WtW[1], WtW[1], 1024, 512 * 1024,
          b.h2, 512, b.h2O, 0, in[38], 0, 0, 0, cptr, bRowc, Rc, r0, Mp, 512, 1024);
    mgemm(st, ME_SIG, 1, 0, b.h2, 512, b.h2O, WtW[2], WtW[2], 512, 256 * 512,
          b.wg, 0, 0, 0, in[40], 0, 0, 0, cptr, bRowc, Rc, r0, Mp, 256, 512);
    // y = uf @ Dcat, fused z0 = soft(y, thr)
    mgemm(st, ME_Y, 3, 0, b.uf, 256, b.ufO, b.DbT, b.DbT + 327680, 256, 163840,
          b.y, 640, 0, b.z, 0, b.thr, 0, 640, cptr, bRowc, Rc, r0, Mp, 624, 256);
    // LISTA iterations (z hi x S split, TERMS=2)
    bf16* zi = b.z; bf16* zo = b.zn;
    for (int it = 0; it < 5; ++it) {
      mgemm(st, ME_SOFT, 2, 0, zi, 640, 0, b.Sb, b.Sb + 819200, 640, 409600,
            zo, 640, 0, 0, 0, b.y, b.thr, 640, cptr, bRowc, Rc, r0, Mp, 624, 640);
      bf16* tmp = zi; zi = zo; zo = tmp;
    }
    // x_pred -> xpT (transposed, clip * Wg), TERMS=2
    mgemm(st, ME_XP, 2, 0, zi, 640, 0, b.Db, b.Db + 327680, 640, 163840,
          b.xp, 0, 0, 0, 0, b.wg, 0, 0, cptr, bRowc, Rc, r0, Mp, 256, 640);
  }
  folddiv_k<<<dim3(128), dim3(256), 0, st>>>(b.xp, b.wg, outimg);
}

extern "C" void kernel_launch(void* const* d_in, const int* in_sizes, int n_in,
                              void* d_out, int out_size, void* d_ws, size_t ws_size,
                              hipStream_t stream)
{
  (void)in_sizes; (void)n_in; (void)out_size;
  const float* const* in = (const float* const*)d_in;
  char* base = (char*)d_ws;
  size_t off = 0;
  auto allocf = [&](size_t nelem) -> float* {
    float* p = (float*)(base + off);
    off += ((nelem * 4 + 255) / 256) * 256;
    return p;
  };
  auto allocb2 = [&](size_t nelem) -> bf16* {  // hi+lo planes
    bf16* p = (bf16*)(base + off);
    off += ((nelem * 2 * 2 + 255) / 256) * 256;
    return p;
  };
  auto allocb1 = [&](size_t nelem) -> bf16* {  // single plane
    bf16* p = (bf16*)(base + off);
    off += ((nelem * 2 + 255) / 256) * 256;
    return p;
  };
  Bufs b;
  b.xp = allocf((size_t)NLR * 256);   // transposed [256][NLR]
  b.wg = allocf((size_t)NLR * 256);   // transposed [256][NLR]
  b.Dcat_f = allocf(2 * 256 * 624);
  b.sd = allocf(224 * 256);
  b.res = allocf(2 * 16384);
  b.Db = allocb2(2 * 163840);
  b.DbT = allocb2(2 * 163840);
  b.Sb = allocb2(2 * 409600);
  b.extb = allocb2(256 * 256);
  b.sdh1 = allocb2(256 * 512);
  b.sdh2 = allocb2(256 * 1024);
  b.sdh3 = allocb2(256 * 512);
  bf16* Wcat1 = allocb1(2 * 3072 * 256);
  bf16* Wcat2 = allocb1(2 * 3072 * 256);
  float* bcat1 = allocf(3072);
  float* bcat2 = allocf(3072);

  // transposed split-bf16 weights (single merged launch)
  // sd: s1..s4; L2/L3 of a,p,b,q,w; merged L1 slices per stage
  bf16 *Wa[3], *Wp[3], *Wb[3], *Wq[3], *Ww[3], *Ws[4];
  WTable wt;
  int ne = 0, tot = 0;
  auto addw = [&](const float* src, bf16* dst, int K, int N, int Kp, int Np, long long loOff) {
    wt.src[ne] = src; wt.dst[ne] = dst;
    wt.K[ne] = K; wt.N[ne] = N; wt.Kp[ne] = Kp; wt.Np[ne] = Np;
    wt.loOff[ne] = loOff; wt.base[ne] = tot;
    tot += Np * Kp; ++ne;
  };
  // sd weights (split, own buffers)
  int sdK[4] = {256, 512, 1024, 512}, sdN[4] = {512, 1024, 512, 256}, sdIdx[4] = {3, 5, 7, 9};
  for (int i = 0; i < 4; ++i) {
    Ws[i] = allocb2((size_t)sdN[i] * sdK[i]);
    addw(in[sdIdx[i]], Ws[i], sdK[i], sdN[i], sdK[i], sdN[i], (long long)sdN[i] * sdK[i]);
  }
  // L2/L3 weights
  struct WD { bf16** slot; int idx, K, N, Kp, Np; };
  WD wd[10] = {
    {&Wa[1], 13, 1024, 512, 1024, 512}, {&Wa[2], 15, 512, 112, 512, 128},
    {&Wp[1], 19, 1024, 512, 1024, 512}, {&Wp[2], 21, 512, 512, 512, 512},
    {&Wb[1], 25, 1024, 512, 1024, 512}, {&Wb[2], 27, 512, 112, 512, 128},
    {&Wq[1], 31, 1024, 512, 1024, 512}, {&Wq[2], 33, 512, 512, 512, 512},
    {&Ww[1], 37, 1024, 512, 1024, 512}, {&Ww[2], 39, 512, 256, 512, 256},
  };
  for (int i = 0; i < 10; ++i) {
    *wd[i].slot = allocb2((size_t)wd[i].Np * wd[i].Kp);
    addw(in[wd[i].idx], *wd[i].slot, wd[i].K, wd[i].N, wd[i].Kp, wd[i].Np,
         (long long)wd[i].Np * wd[i].Kp);
  }
  // merged L1 slices: layout [2pl][3][1024][256]; stage1 = (p17, a11, w35), stage2 = (q29, b23, w35)
  const long long catLo = 3072LL * 256;
  addw(in[17], Wcat1 + 0 * 262144, 256, 1024, 256, 1024, catLo);
  addw(in[11], Wcat1 + 1 * 262144, 256, 1024, 256, 1024, catLo);
  addw(in[35], Wcat1 + 2 * 262144, 256, 1024, 256, 1024, catLo);
  addw(in[29], Wcat2 + 0 * 262144, 256, 1024, 256, 1024, catLo);
  addw(in[23], Wcat2 + 1 * 262144, 256, 1024, 256, 1024, catLo);
  addw(in[35], Wcat2 + 2 * 262144, 256, 1024, 256, 1024, catLo);
  wt.base[NW] = tot;
  wtransall_k<<<dim3((tot + 255) / 256), dim3(256), 0, stream>>>(wt);
  biascat_k<<<dim3(12), dim3(256), 0, stream>>>(in[18], in[12], in[36], in[30], in[24],
                                                bcat1, bcat2);

  // chunk size (per batch-row bytes: uf 1024 + h1all 6144 + h2 2048 + z 1280 +
  // zn 1280 + thr 2560 + y 2560 = 16896; chunk holds 2R rows)
  long long avail = (long long)ws_size - (long long)off - (1 << 20);
  long long perrow2 = 2LL * (16896 + 64);
  int R = 12800;
  if (avail / perrow2 < 12800) R = (int)(avail / perrow2);
  R &= ~127;
  if (R < 128) R = 128;
  b.R = R;
  size_t rows2 = (size_t)2 * R;
  b.uf = allocb2(rows2 * 256);  b.ufO = rows2 * 256;
  b.h1 = allocb1(rows2 * 3072);                       // merged hi-only
  b.h2 = allocb2(rows2 * 512);  b.h2O = rows2 * 512;  // hi+lo (L3 TERMS=3)
  b.z = allocb1(rows2 * 640);
  b.zn = allocb1(rows2 * 640);
  b.thr = allocf(rows2 * 640);
  b.y = allocf(rows2 * 640);

  // stage 1: pd = p*(17), lam = a*(11); stage 2: pd = q*(29), lam = b*(23)
  run_stage(stream, in, in[0], b.res, 17, 11, Wcat1, bcat1, Wp, Wa, Ww, Ws, b);
  run_stage(stream, in, b.res, (float*)d_out, 29, 23, Wcat2, bcat2, Wq, Wb, Ww, Ws, b);
}

// Round 9
// 3189.100 us; speedup vs baseline: 1.2056x; 1.2056x over previous
//
#include <hip/hip_runtime.h>
#include <hip/hip_bf16.h>
#include <math.h>

#define L_LOC 12769              // 113*113 sliding-window positions
#define NB 2
#define NLR (NB * L_LOC)
#define NW 19

typedef short short8v __attribute__((ext_vector_type(8)));
typedef float f32x4 __attribute__((ext_vector_type(4)));
typedef __hip_bfloat16 bf16;

__device__ __forceinline__ float softf(float x, float l) {
  float a = fmaxf(fabsf(x) - l, 0.0f);
  return x > 0.0f ? a : (x < 0.0f ? -a : 0.0f);
}
__device__ __forceinline__ float sigf(float x) { return 1.0f / (1.0f + expf(-x)); }
__device__ __forceinline__ void split2(float v, bf16& h, bf16& l) {
  h = __float2bfloat16(v);
  l = __float2bfloat16(v - __bfloat162float(h));
}

// ================= split-bf16 MFMA GEMM ========================================
// A: hi plane at A, lo at A+aOff. B per batch (B0/B1 by m0>=bRow), lo at +bOff.
// TERMS=3: Ah*Bh + Ah*Bl + Al*Bh.  TERMS=2: Ah*(Bh+Bl).  TERMS=1: Ah*Bh.
enum { ME_RELU = 0, ME_SCALE = 1, ME_SIG = 2, ME_Y = 3, ME_SOFT = 4, ME_XP = 5,
       ME_SMAT = 6, ME_LIN = 7 };

template <int EPI, int TERMS, int WLO>
__global__ __launch_bounds__(256) void mgemm_k(
    const bf16* __restrict__ A, int lda, size_t aOff,
    const bf16* __restrict__ B0, const bf16* __restrict__ B1, int ldb, size_t bOff,
    void* __restrict__ Cv, int ldc, size_t cOff,
    bf16* __restrict__ Zp,
    const float* __restrict__ bias,
    const float* __restrict__ E1, const float* __restrict__ E2, int lde,
    const float* __restrict__ cptr, int bRow, int Rc, int r0, int N, int K)
{
  const int NPA = (TERMS >= 3) ? 2 : 1;
  const int NPB = (TERMS >= 2) ? 2 : 1;
  __shared__ char As[(TERMS >= 3) ? 2 : 1][8192];   // [pl][128 rows][32 k] bf16
  __shared__ char Bs[(TERMS >= 2) ? 2 : 1][8192];
  const int t = threadIdx.x;
  const int lane = t & 63, wv = t >> 6;
  const int wr = wv >> 1, wc = wv & 1;
  const int m0 = blockIdx.x * 128, n0 = blockIdx.y * 128;
  const int nb = (m0 >= bRow) ? 1 : 0;
  const bf16* __restrict__ Bt = nb ? B1 : B0;
  const int row16 = lane & 15, kg = lane >> 4;
  const int grow = t >> 2;
  const int gcol = (t & 3) * 8;
  f32x4 acc[4][4];
#pragma unroll
  for (int i = 0; i < 4; ++i)
#pragma unroll
    for (int j = 0; j < 4; ++j) { acc[i][j][0] = 0.f; acc[i][j][1] = 0.f; acc[i][j][2] = 0.f; acc[i][j][3] = 0.f; }

  for (int k0 = 0; k0 < K; k0 += 32) {
#pragma unroll
    for (int h = 0; h < NPA; ++h)
#pragma unroll
      for (int i = 0; i < 2; ++i) {
        const bf16* ga = A + h * aOff + (size_t)(m0 + i * 64 + grow) * lda + k0 + gcol;
        __builtin_amdgcn_global_load_lds(
            (const __attribute__((address_space(1))) void*)ga,
            (__attribute__((address_space(3))) void*)(As[h] + i * 4096 + wv * 1024), 16, 0, 0);
      }
#pragma unroll
    for (int h = 0; h < NPB; ++h)
#pragma unroll
      for (int i = 0; i < 2; ++i) {
        const bf16* gb = Bt + h * bOff + (size_t)(n0 + i * 64 + grow) * ldb + k0 + gcol;
        __builtin_amdgcn_global_load_lds(
            (const __attribute__((address_space(1))) void*)gb,
            (__attribute__((address_space(3))) void*)(Bs[h] + i * 4096 + wv * 1024), 16, 0, 0);
      }
    __syncthreads();
    short8v ah[4], al[4], bh[4], bl[4];
#pragma unroll
    for (int mi = 0; mi < 4; ++mi) {
      int o = (wr * 64 + mi * 16 + row16) * 64 + kg * 16;
      ah[mi] = *(const short8v*)(As[0] + o);
      if (TERMS >= 3) al[mi] = *(const short8v*)(As[NPA - 1] + o);
    }
#pragma unroll
    for (int ni = 0; ni < 4; ++ni) {
      int o = (wc * 64 + ni * 16 + row16) * 64 + kg * 16;
      bh[ni] = *(const short8v*)(Bs[0] + o);
      if (TERMS >= 2) bl[ni] = *(const short8v*)(Bs[NPB - 1] + o);
    }
#pragma unroll
    for (int mi = 0; mi < 4; ++mi)
#pragma unroll
      for (int ni = 0; ni < 4; ++ni) {
        if (TERMS >= 2)
          acc[mi][ni] = __builtin_amdgcn_mfma_f32_16x16x32_bf16(ah[mi], bl[ni], acc[mi][ni], 0, 0, 0);
        if (TERMS >= 3)
          acc[mi][ni] = __builtin_amdgcn_mfma_f32_16x16x32_bf16(al[mi], bh[ni], acc[mi][ni], 0, 0, 0);
        acc[mi][ni] = __builtin_amdgcn_mfma_f32_16x16x32_bf16(ah[mi], bh[ni], acc[mi][ni], 0, 0, 0);
      }
    __syncthreads();
  }

  float invc = 1.0f;
  if (EPI == ME_SCALE || EPI == ME_SOFT || EPI == ME_SMAT) invc = 1.0f / cptr[0];
  bf16* Cb = (bf16*)Cv;
  float* Cf = (float*)Cv;
#pragma unroll
  for (int ni = 0; ni < 4; ++ni) {
    int col = n0 + wc * 64 + ni * 16 + row16;
    const bool colok = col < N;
    float bv = 0.0f;
    if ((EPI == ME_RELU || EPI == ME_SCALE || EPI == ME_SIG || EPI == ME_LIN) && colok)
      bv = bias[col];
#pragma unroll
    for (int mi = 0; mi < 4; ++mi) {
      int rowb = m0 + wr * 64 + mi * 16 + kg * 4;
#pragma unroll
      for (int r = 0; r < 4; ++r) {
        int row = rowb + r;
        float v = acc[mi][ni][r];
        if (EPI == ME_RELU) {
          if (colok) {
            float o = fmaxf(v + bv, 0.0f);
            size_t ci = (size_t)row * ldc + col;
            if (WLO) {
              bf16 h, l; split2(o, h, l);
              Cb[ci] = h; Cb[ci + cOff] = l;
            } else {
              Cb[ci] = __float2bfloat16(o);
            }
          }
        } else if (EPI == ME_LIN) {
          if (colok && row < Rc) Cf[(size_t)row * ldc + col] = v + bv;
        } else if (EPI == ME_SCALE) {
          if (colok) Cf[(size_t)row * ldc + col] = (v + bv) * invc;
        } else if (EPI == ME_SIG) {
          if (colok) {
            int rl = row - nb * bRow;
            if (rl < Rc && rl >= 0)
              Cf[(size_t)col * NLR + (size_t)nb * L_LOC + r0 + rl] = sigf(v + bv);
          }
        } else if (EPI == ME_Y) {
          if (colok) {
            size_t e = (size_t)row * lde + col;
            Cf[(size_t)row * ldc + col] = v;
            Zp[(size_t)row * 640 + col] = __float2bfloat16(softf(v, E1[e]));
          }
        } else if (EPI == ME_SOFT) {
          if (colok) {
            size_t e = (size_t)row * lde + col;
            Cb[(size_t)row * ldc + col] = __float2bfloat16(softf(v + E1[e] * invc, E2[e]));
          }
        } else if (EPI == ME_XP) {
          int rl = row - nb * bRow;
          if (colok && rl < Rc && rl >= 0) {
            size_t g = (size_t)col * NLR + (size_t)nb * L_LOC + r0 + rl;
            Cf[g] = fminf(fmaxf(v, 0.0f), 1.0f) * E1[g];
          }
        } else { // ME_SMAT: write split S directly, zero pads
          float o = (row < 624 && col < 624) ? ((row == col ? 1.0f : 0.0f) - v * invc) : 0.0f;
          bf16 h, l; split2(o, h, l);
          size_t ci = (size_t)row * ldc + col;
          Cb[ci] = h; Cb[ci + cOff] = l;
        }
      }
    }
  }
}

static void mgemm(hipStream_t st, int EPI, int terms, int wlo,
                  const bf16* A, int lda, size_t aOff,
                  const bf16* B0, const bf16* B1, int ldb, size_t bOff,
                  void* C, int ldc, size_t cOff,
                  bf16* Zp,
                  const float* bias, const float* E1, const float* E2, int lde,
                  const float* cptr, int bRow, int Rc, int r0,
                  int Mp, int N, int K)
{
  dim3 grid(Mp / 128, (N + 127) / 128), blk(256);
#define MG(ep, tm, wl) mgemm_k<ep, tm, wl><<<grid, blk, 0, st>>>(A, lda, aOff, B0, B1, ldb, bOff, C, ldc, cOff, Zp, bias, E1, E2, lde, cptr, bRow, Rc, r0, N, K)
  if (EPI == ME_RELU && terms == 1 && !wlo) { MG(ME_RELU, 1, 0); }
  else if (EPI == ME_RELU && terms == 1)    { MG(ME_RELU, 1, 1); }
  else if (EPI == ME_RELU)                  { MG(ME_RELU, 3, 1); }
  else if (EPI == ME_LIN)                   { MG(ME_LIN, 3, 0); }
  else if (EPI == ME_SCALE)                 { MG(ME_SCALE, 3, 0); }
  else if (EPI == ME_SIG)                   { MG(ME_SIG, 1, 0); }
  else if (EPI == ME_Y)                     { MG(ME_Y, 3, 0); }
  else if (EPI == ME_SOFT)                  { MG(ME_SOFT, 2, 0); }
  else if (EPI == ME_XP)                    { MG(ME_XP, 2, 0); }
  else                                      { MG(ME_SMAT, 3, 0); }
#undef MG
}

// ================= small kernels ==============================================
struct WTable {
  const float* src[NW];
  bf16* dst[NW];
  int K[NW], N[NW], Kp[NW], Np[NW];
  long long loOff[NW];
  int base[NW + 1];
};

__global__ void wtransall_k(WTable w) {
  int idx = blockIdx.x * 256 + threadIdx.x;
  if (idx >= w.base[NW]) return;
  int s = 0;
  while (s < NW - 1 && idx >= w.base[s + 1]) ++s;
  int li = idx - w.base[s];
  int Kp = w.Kp[s];
  int n = li / Kp, k = li - n * Kp;
  float v = (n < w.N[s] && k < w.K[s]) ? w.src[s][(size_t)k * w.N[s] + n] : 0.0f;
  bf16 h, l; split2(v, h, l);
  w.dst[s][li] = h;
  w.dst[s][li + w.loOff[s]] = l;
}

// ext rows (stride-8 unfold) -> split bf16 [2pl][256 rows][256], pad rows zero
__global__ void extb_k(const float* __restrict__ img, bf16* __restrict__ dst) {
  int idx = blockIdx.x * 256 + threadIdx.x;   // 256*256
  int row = idx >> 8, p = idx & 255;
  float v = 0.0f;
  if (row < 224) {
    int n = row / 112, e = row - n * 112;
    int l1 = 2 * e, i1 = l1 / 15, j1 = l1 - i1 * 15;
    v = img[n * 16384 + (8 * i1 + (p >> 4)) * 128 + 8 * j1 + (p & 15)];
  }
  bf16 h, l; split2(v, h, l);
  dst[idx] = h; dst[idx + 65536] = l;
}

__global__ void rownorm224_k(float* sd) {
  int r = blockIdx.x, t = threadIdx.x;   // 224 blocks x 64 threads
  float v[4], s = 0.0f;
#pragma unroll
  for (int j = 0; j < 4; ++j) { v[j] = sd[r * 256 + t + 64 * j]; s += v[j] * v[j]; }
#pragma unroll
  for (int o = 1; o < 64; o <<= 1) s += __shfl_xor(s, o);
  float sc = 1.0f / fmaxf(sqrtf(s), 1e-12f);
#pragma unroll
  for (int j = 0; j < 4; ++j) sd[r * 256 + t + 64 * j] = v[j] * sc;
}

// ---- CBAM, multi-block ----
__global__ void meanmax_k(const float* __restrict__ sd, float* mv, float* xv) {
  int id = blockIdx.x * 256 + threadIdx.x;   // 512
  int n = id >> 8, ch = id & 255;
  float s = 0.0f, m = -INFINITY;
  for (int e = 0; e < 112; ++e) {
    float v = sd[(n * 112 + e) * 256 + ch];
    s += v; m = fmaxf(m, v);
  }
  mv[id] = s * (1.0f / 112.0f);
  xv[id] = m;
}

__global__ void cah_k(const float* __restrict__ mv, const float* __restrict__ xv,
                      const float* __restrict__ w1, float* hm, float* hx) {
  int id = blockIdx.x * 256 + threadIdx.x;   // 1024 (4 blocks)
  int n = id >> 9, o = id & 511;
  float sm = 0.0f, sx = 0.0f;
#pragma unroll 4
  for (int i = 0; i < 256; ++i) {
    float w = w1[i * 512 + o];
    sm = fmaf(mv[n * 256 + i], w, sm);
    sx = fmaf(xv[n * 256 + i], w, sx);
  }
  hm[id] = fmaxf(sm, 0.0f);
  hx[id] = fmaxf(sx, 0.0f);
}

__global__ void cao_k(const float* __restrict__ hm, const float* __restrict__ hx,
                      const float* __restrict__ w2, float* ca) {
  int id = blockIdx.x * 256 + threadIdx.x;   // 512 (2 blocks)
  int n = id >> 8, ch = id & 255;
  float s = 0.0f;
#pragma unroll 4
  for (int o = 0; o < 512; ++o)
    s = fmaf(hm[n * 512 + o] + hx[n * 512 + o], w2[o * 256 + ch], s);
  ca[id] = sigf(s);
}

// per-batch: channel-attend + spatial mean/max + 7x7 conv + scale into Dcat_f
__global__ void spatial_k(const float* __restrict__ sd, const float* __restrict__ ca,
                          const float* __restrict__ saw, float* __restrict__ Dcat) {
  __shared__ float smean[112], smax[112];
  const int n = blockIdx.x, t = threadIdx.x;   // 2 blocks x 128
  if (t < 112) {
    float sum = 0.0f, mx = -INFINITY;
    for (int ch = 0; ch < 256; ++ch) {
      float v = sd[(n * 112 + t) * 256 + ch] * ca[n * 256 + ch];
      Dcat[(size_t)n * 159744 + ch * 624 + 512 + t] = v;
      sum += v; mx = fmaxf(mx, v);
    }
    smean[t] = sum * (1.0f / 256.0f);
    smax[t] = mx;
  }
  __syncthreads();
  if (t < 112) {
    int h = t / 14, w = t % 14;
    float acc = 0.0f;
    for (int dh = 0; dh < 7; ++dh) {
      int hh = h + dh - 3; if (hh < 0 || hh >= 8) continue;
      for (int dw = 0; dw < 7; ++dw) {
        int ww = w + dw - 3; if (ww < 0 || ww >= 14) continue;
        int sp = hh * 14 + ww;
        acc += smean[sp] * saw[dh * 7 + dw] + smax[sp] * saw[49 + dh * 7 + dw];
      }
    }
    float sg = sigf(acc);
    for (int ch = 0; ch < 256; ++ch) Dcat[(size_t)n * 159744 + ch * 624 + 512 + t] *= sg;
  }
}

// Dict [256][512] + Dcat_f sd-part -> Db [n][2pl][256][640], DbT [n][2pl][640][256]
__global__ void dcatconv_k(const float* __restrict__ Dict, const float* __restrict__ Dc,
                           bf16* __restrict__ Db, bf16* __restrict__ DbT) {
  int idx = blockIdx.x * 256 + threadIdx.x;   // 2*256*640
  if (idx >= 327680) return;
  int n = idx / 163840, r = idx - n * 163840;
  int p = r / 640, a = r - p * 640;
  float v = 0.0f;
  if (a < 512)      v = Dict[p * 512 + a];
  else if (a < 624) v = Dc[(size_t)n * 159744 + p * 624 + a];
  bf16 h, l; split2(v, h, l);
  size_t base = (size_t)n * 327680;
  Db[base + p * 640 + a] = h;
  Db[base + 163840 + p * 640 + a] = l;
  DbT[base + (size_t)a * 256 + p] = h;
  DbT[base + 163840 + (size_t)a * 256 + p] = l;
}

// unfold for both batches into the stacked chunk buffer
__global__ void unfold_k(const float* __restrict__ img, bf16* __restrict__ uf,
                         int r0, int Rc, int bRowc, size_t pOff) {
  int bi = blockIdx.x;               // 0..2*Rc-1
  int nb = bi >= Rc;
  int rl = nb ? bi - Rc : bi;
  int row = nb * bRowc + rl;
  int p = threadIdx.x;
  int l = r0 + rl;
  int i0 = l / 113, j0 = l - i0 * 113;
  float v = img[nb * 16384 + (i0 + (p >> 4)) * 128 + j0 + (p & 15)];
  bf16 h, lo; split2(v, h, lo);
  size_t o = (size_t)row * 256 + p;
  uf[o] = h; uf[o + pOff] = lo;
}

// overlap-add fold + divide; xpT/wgT are [256 patch][NLR row] (coalesced reads)
__global__ void folddiv_k(const float* __restrict__ xpT, const float* __restrict__ wgT,
                          float* __restrict__ out) {
  int idx = blockIdx.x * 256 + threadIdx.x;
  if (idx >= 32768) return;
  int n = idx >> 14, rem = idx & 16383;
  int i = rem >> 7, j = rem & 127;
  float num = 0.0f, den = 0.0f;
  int kh0 = (i - 112 > 0) ? i - 112 : 0;
  int kh1 = (i < 15) ? i : 15;
  int kw0 = (j - 112 > 0) ? j - 112 : 0;
  int kw1 = (j < 15) ? j : 15;
  for (int kh = kh0; kh <= kh1; ++kh)
    for (int kw = kw0; kw <= kw1; ++kw) {
      int l = (i - kh) * 113 + (j - kw);
      size_t base = (size_t)(kh * 16 + kw) * NLR + (size_t)n * L_LOC + l;
      num += xpT[base];
      den += wgT[base];
    }
  out[idx] = num / den;
}

// ================= host orchestration ==========================================
struct Bufs {
  float *xp, *wg, *Dcat_f, *sd, *res;
  float *mv, *xv, *hm, *hx, *ca;
  bf16 *Db, *DbT, *Sb;
  bf16 *extb, *sdh1, *sdh2, *sdh3;
  bf16 *uf, *h1, *h2, *z, *zn;
  float *thr, *y;
  size_t ufO, h2O;
  int R;
};

static void run_stage(hipStream_t st, const float* const* in, const float* img,
                      float* outimg, int pd0, int lam0,
                      bf16* const* WtPd, bf16* const* WtLam, bf16* const* WtW,
                      bf16* const* Ws, const Bufs& b)
{
  const float* cptr = in[2];
  const int BIG = 1 << 30;
  // --- adaptive dictionary pipeline via MFMA (TERMS=3 ~ fp32) ---
  extb_k<<<dim3(256), dim3(256), 0, st>>>(img, b.extb);
  mgemm(st, ME_RELU, 3, 1, b.extb, 256, 65536, Ws[0], Ws[0], 256, 512 * 256,
        b.sdh1, 512, 256 * 512, 0, in[4], 0, 0, 0, cptr, BIG, 224, 0, 256, 512, 256);
  mgemm(st, ME_RELU, 3, 1, b.sdh1, 512, 256 * 512, Ws[1], Ws[1], 512, 1024 * 512,
        b.sdh2, 1024, 256 * 1024, 0, in[6], 0, 0, 0, cptr, BIG, 224, 0, 256, 1024, 512);
  mgemm(st, ME_RELU, 3, 1, b.sdh2, 1024, 256 * 1024, Ws[2], Ws[2], 1024, 512 * 1024,
        b.sdh3, 512, 256 * 512, 0, in[8], 0, 0, 0, cptr, BIG, 224, 0, 256, 512, 1024);
  mgemm(st, ME_LIN, 3, 0, b.sdh3, 512, 256 * 512, Ws[3], Ws[3], 512, 256 * 512,
        b.sd, 256, 0, 0, in[10], 0, 0, 0, cptr, BIG, 224, 0, 256, 256, 512);
  rownorm224_k<<<dim3(224), dim3(64), 0, st>>>(b.sd);
  // CBAM, multi-block
  meanmax_k<<<dim3(2), dim3(256), 0, st>>>(b.sd, b.mv, b.xv);
  cah_k<<<dim3(4), dim3(256), 0, st>>>(b.mv, b.xv, in[41], b.hm, b.hx);
  cao_k<<<dim3(2), dim3(256), 0, st>>>(b.hm, b.hx, in[42], b.ca);
  spatial_k<<<dim3(2), dim3(128), 0, st>>>(b.sd, b.ca, in[43], b.Dcat_f);
  dcatconv_k<<<dim3(1280), dim3(256), 0, st>>>(in[1], b.Dcat_f, b.Db, b.DbT);
  // --- S = I - D^T D / c via split MFMA, fused split-bf16 output ---
  for (int n = 0; n < NB; ++n) {
    const bf16* Dt = b.DbT + (size_t)n * 327680;
    mgemm(st, ME_SMAT, 3, 0, Dt, 256, 163840, Dt, Dt, 256, 163840,
          b.Sb + (size_t)n * 819200, 640, 409600, 0,
          0, 0, 0, 0, cptr, BIG, 624, 0, 640, 640, 256);
  }

  // --- stacked both-batch chunks ---
  for (int r0 = 0; r0 < L_LOC; r0 += b.R) {
    int Rc = L_LOC - r0; if (Rc > b.R) Rc = b.R;
    int bRowc = ((Rc + 127) / 128) * 128;
    int Mp = 2 * bRowc;
    unfold_k<<<dim3(2 * Rc), dim3(256), 0, st>>>(img, b.uf, r0, Rc, bRowc, b.ufO);
    // pd MLP -> thr[:, :512]
    mgemm(st, ME_RELU, 1, 0, b.uf, 256, b.ufO, WtPd[0], WtPd[0], 256, 1024 * 256,
          b.h1, 1024, 0, 0, in[pd0 + 1], 0, 0, 0, cptr, bRowc, Rc, r0, Mp, 1024, 256);
    mgemm(st, ME_RELU, 1, 1, b.h1, 1024, 0, WtPd[1], WtPd[1], 1024, 512 * 1024,
          b.h2, 512, b.h2O, 0, in[pd0 + 3], 0, 0, 0, cptr, bRowc, Rc, r0, Mp, 512, 1024);
    mgemm(st, ME_SCALE, 3, 0, b.h2, 512, b.h2O, WtPd[2], WtPd[2], 512, 512 * 512,
          b.thr, 640, 0, 0, in[pd0 + 5], 0, 0, 0, cptr, bRowc, Rc, r0, Mp, 512, 512);
    // lam MLP -> thr[:, 512:624]
    mgemm(st, ME_RELU, 1, 0, b.uf, 256, b.ufO, WtLam[0], WtLam[0], 256, 1024 * 256,
          b.h1, 1024, 0, 0, in[lam0 + 1], 0, 0, 0, cptr, bRowc, Rc, r0, Mp, 1024, 256);
    mgemm(st, ME_RELU, 1, 1, b.h1, 1024, 0, WtLam[1], WtLam[1], 1024, 512 * 1024,
          b.h2, 512, b.h2O, 0, in[lam0 + 3], 0, 0, 0, cptr, bRowc, Rc, r0, Mp, 512, 1024);
    mgemm(st, ME_SCALE, 3, 0, b.h2, 512, b.h2O, WtLam[2], WtLam[2], 512, 128 * 512,
          b.thr + 512, 640, 0, 0, in[lam0 + 5], 0, 0, 0, cptr, bRowc, Rc, r0, Mp, 112, 512);
    // w MLP -> WgT (transposed, sigmoid)
    mgemm(st, ME_RELU, 1, 0, b.uf, 256, b.ufO, WtW[0], WtW[0], 256, 1024 * 256,
          b.h1, 1024, 0, 0, in[36], 0, 0, 0, cptr, bRowc, Rc, r0, Mp, 1024, 256);
    mgemm(st, ME_RELU, 1, 1, b.h1, 1024, 0, WtW[1], WtW[1], 1024, 512 * 1024,
          b.h2, 512, b.h2O, 0, in[38], 0, 0, 0, cptr, bRowc, Rc, r0, Mp, 512, 1024);
    mgemm(st, ME_SIG, 1, 0, b.h2, 512, b.h2O, WtW[2], WtW[2], 512, 256 * 512,
          b.wg, 0, 0, 0, in[40], 0, 0, 0, cptr, bRowc, Rc, r0, Mp, 256, 512);
    // y = uf @ Dcat, fused z0 = soft(y, thr)
    mgemm(st, ME_Y, 3, 0, b.uf, 256, b.ufO, b.DbT, b.DbT + 327680, 256, 163840,
          b.y, 640, 0, b.z, 0, b.thr, 0, 640, cptr, bRowc, Rc, r0, Mp, 624, 256);
    // LISTA iterations (z hi x S split, TERMS=2)
    bf16* zi = b.z; bf16* zo = b.zn;
    for (int it = 0; it < 5; ++it) {
      mgemm(st, ME_SOFT, 2, 0, zi, 640, 0, b.Sb, b.Sb + 819200, 640, 409600,
            zo, 640, 0, 0, 0, b.y, b.thr, 640, cptr, bRowc, Rc, r0, Mp, 624, 640);
      bf16* tmp = zi; zi = zo; zo = tmp;
    }
    // x_pred -> xpT (transposed, clip * Wg), TERMS=2
    mgemm(st, ME_XP, 2, 0, zi, 640, 0, b.Db, b.Db + 327680, 640, 163840,
          b.xp, 0, 0, 0, 0, b.wg, 0, 0, cptr, bRowc, Rc, r0, Mp, 256, 640);
  }
  folddiv_k<<<dim3(128), dim3(256), 0, st>>>(b.xp, b.wg, outimg);
}

extern "C" void kernel_launch(void* const* d_in, const int* in_sizes, int n_in,
                              void* d_out, int out_size, void* d_ws, size_t ws_size,
                              hipStream_t stream)
{
  (void)in_sizes; (void)n_in; (void)out_size;
  const float* const* in = (const float* const*)d_in;
  char* base = (char*)d_ws;
  size_t off = 0;
  auto allocf = [&](size_t nelem) -> float* {
    float* p = (float*)(base + off);
    off += ((nelem * 4 + 255) / 256) * 256;
    return p;
  };
  auto allocb2 = [&](size_t nelem) -> bf16* {  // hi+lo planes
    bf16* p = (bf16*)(base + off);
    off += ((nelem * 2 * 2 + 255) / 256) * 256;
    return p;
  };
  auto allocb1 = [&](size_t nelem) -> bf16* {  // single plane
    bf16* p = (bf16*)(base + off);
    off += ((nelem * 2 + 255) / 256) * 256;
    return p;
  };
  Bufs b;
  b.xp = allocf((size_t)NLR * 256);   // transposed [256][NLR]
  b.wg = allocf((size_t)NLR * 256);   // transposed [256][NLR]
  b.Dcat_f = allocf(2 * 256 * 624);
  b.sd = allocf(224 * 256);
  b.res = allocf(2 * 16384);
  b.mv = allocf(512); b.xv = allocf(512);
  b.hm = allocf(1024); b.hx = allocf(1024);
  b.ca = allocf(512);
  b.Db = allocb2(2 * 163840);
  b.DbT = allocb2(2 * 163840);
  b.Sb = allocb2(2 * 409600);
  b.extb = allocb2(256 * 256);
  b.sdh1 = allocb2(256 * 512);
  b.sdh2 = allocb2(256 * 1024);
  b.sdh3 = allocb2(256 * 512);

  // transposed split-bf16 weights (single merged launch)
  bf16 *Wa[3], *Wp[3], *Wb[3], *Wq[3], *Ww[3], *Ws[4];
  WTable wt;
  int ne = 0, tot = 0;
  auto addw = [&](const float* src, bf16* dst, int K, int N, int Kp, int Np) {
    wt.src[ne] = src; wt.dst[ne] = dst;
    wt.K[ne] = K; wt.N[ne] = N; wt.Kp[ne] = Kp; wt.Np[ne] = Np;
    wt.loOff[ne] = (long long)Np * Kp; wt.base[ne] = tot;
    tot += Np * Kp; ++ne;
  };
  int sdK[4] = {256, 512, 1024, 512}, sdN[4] = {512, 1024, 512, 256}, sdIdx[4] = {3, 5, 7, 9};
  for (int i = 0; i < 4; ++i) {
    Ws[i] = allocb2((size_t)sdN[i] * sdK[i]);
    addw(in[sdIdx[i]], Ws[i], sdK[i], sdN[i], sdK[i], sdN[i]);
  }
  struct WD { bf16** slot; int idx, K, N, Kp, Np; };
  WD wd[15] = {
    {&Wa[0], 11, 256, 1024, 256, 1024}, {&Wa[1], 13, 1024, 512, 1024, 512}, {&Wa[2], 15, 512, 112, 512, 128},
    {&Wp[0], 17, 256, 1024, 256, 1024}, {&Wp[1], 19, 1024, 512, 1024, 512}, {&Wp[2], 21, 512, 512, 512, 512},
    {&Wb[0], 23, 256, 1024, 256, 1024}, {&Wb[1], 25, 1024, 512, 1024, 512}, {&Wb[2], 27, 512, 112, 512, 128},
    {&Wq[0], 29, 256, 1024, 256, 1024}, {&Wq[1], 31, 1024, 512, 1024, 512}, {&Wq[2], 33, 512, 512, 512, 512},
    {&Ww[0], 35, 256, 1024, 256, 1024}, {&Ww[1], 37, 1024, 512, 1024, 512}, {&Ww[2], 39, 512, 256, 512, 256},
  };
  for (int i = 0; i < 15; ++i) {
    *wd[i].slot = allocb2((size_t)wd[i].Np * wd[i].Kp);
    addw(in[wd[i].idx], *wd[i].slot, wd[i].K, wd[i].N, wd[i].Kp, wd[i].Np);
  }
  wt.base[NW] = tot;
  wtransall_k<<<dim3((tot + 255) / 256), dim3(256), 0, stream>>>(wt);

  // chunk size (per batch-row bytes: uf 1024 + h1 2048 + h2 2048 + z 1280 +
  // zn 1280 + thr 2560 + y 2560 = 12800; chunk holds 2R rows)
  long long avail = (long long)ws_size - (long long)off - (1 << 20);
  long long perrow2 = 2LL * (12800 + 64);
  int R = 12800;
  if (avail / perrow2 < 12800) R = (int)(avail / perrow2);
  R &= ~127;
  if (R < 128) R = 128;
  b.R = R;
  size_t rows2 = (size_t)2 * R;
  b.uf = allocb2(rows2 * 256);  b.ufO = rows2 * 256;
  b.h1 = allocb1(rows2 * 1024);                       // hi only, reused 3x
  b.h2 = allocb2(rows2 * 512);  b.h2O = rows2 * 512;  // hi+lo (L3 TERMS=3)
  b.z = allocb1(rows2 * 640);
  b.zn = allocb1(rows2 * 640);
  b.thr = allocf(rows2 * 640);
  b.y = allocf(rows2 * 640);

  // stage 1: pd = p*(17), lam = a*(11); stage 2: pd = q*(29), lam = b*(23)
  run_stage(stream, in, in[0], b.res, 17, 11, Wp, Wa, Ww, Ws, b);
  run_stage(stream, in, b.res, (float*)d_out, 29, 23, Wq, Wb, Ww, Ws, b);
}

// Round 10
// 3144.160 us; speedup vs baseline: 1.2228x; 1.0143x over previous
//
#include <hip/hip_runtime.h>
#include <hip/hip_bf16.h>
#include <math.h>

#define L_LOC 12769              // 113*113 sliding-window positions
#define NB 2
#define NLR (NB * L_LOC)
#define NW 19

typedef short short8v __attribute__((ext_vector_type(8)));
typedef float f32x4 __attribute__((ext_vector_type(4)));
typedef __hip_bfloat16 bf16;

__device__ __forceinline__ float softf(float x, float l) {
  float a = fmaxf(fabsf(x) - l, 0.0f);
  return x > 0.0f ? a : (x < 0.0f ? -a : 0.0f);
}
__device__ __forceinline__ float sigf(float x) { return 1.0f / (1.0f + expf(-x)); }
__device__ __forceinline__ void split2(float v, bf16& h, bf16& l) {
  h = __float2bfloat16(v);
  l = __float2bfloat16(v - __bfloat162float(h));
}

// ================= split-bf16 MFMA GEMM ========================================
// A: hi plane at A, lo at A+aOff. B per batch (B0/B1 by m0>=bRow), lo at +bOff.
// TERMS=3: Ah*Bh + Ah*Bl + Al*Bh.  TERMS=2: Ah*(Bh+Bl).  TERMS=1: Ah*Bh.
// ME_SOFT (TERMS=1): S has zeroed diag in bf16; exact fp32 diag Dg added via
//   v += z[row,col]*Dg[nb*640+col] in the epilogue (Zp = z input pointer).
enum { ME_RELU = 0, ME_SCALE = 1, ME_SIG = 2, ME_Y = 3, ME_SOFT = 4, ME_XP = 5,
       ME_SMAT = 6, ME_LIN = 7 };

template <int EPI, int TERMS, int WLO>
__global__ __launch_bounds__(256) void mgemm_k(
    const bf16* __restrict__ A, int lda, size_t aOff,
    const bf16* __restrict__ B0, const bf16* __restrict__ B1, int ldb, size_t bOff,
    void* __restrict__ Cv, int ldc, size_t cOff,
    bf16* __restrict__ Zp, float* __restrict__ Dg,
    const float* __restrict__ bias,
    const float* __restrict__ E1, const float* __restrict__ E2, int lde,
    const float* __restrict__ cptr, int bRow, int Rc, int r0, int N, int K)
{
  const int NPA = (TERMS >= 3) ? 2 : 1;
  const int NPB = (TERMS >= 2) ? 2 : 1;
  __shared__ char As[(TERMS >= 3) ? 2 : 1][8192];   // [pl][128 rows][32 k] bf16
  __shared__ char Bs[(TERMS >= 2) ? 2 : 1][8192];
  const int t = threadIdx.x;
  const int lane = t & 63, wv = t >> 6;
  const int wr = wv >> 1, wc = wv & 1;
  const int m0 = blockIdx.x * 128, n0 = blockIdx.y * 128;
  const int nb = (m0 >= bRow) ? 1 : 0;
  const bf16* __restrict__ Bt = nb ? B1 : B0;
  const int row16 = lane & 15, kg = lane >> 4;
  const int grow = t >> 2;
  const int gcol = (t & 3) * 8;
  f32x4 acc[4][4];
#pragma unroll
  for (int i = 0; i < 4; ++i)
#pragma unroll
    for (int j = 0; j < 4; ++j) { acc[i][j][0] = 0.f; acc[i][j][1] = 0.f; acc[i][j][2] = 0.f; acc[i][j][3] = 0.f; }

  for (int k0 = 0; k0 < K; k0 += 32) {
#pragma unroll
    for (int h = 0; h < NPA; ++h)
#pragma unroll
      for (int i = 0; i < 2; ++i) {
        const bf16* ga = A + h * aOff + (size_t)(m0 + i * 64 + grow) * lda + k0 + gcol;
        __builtin_amdgcn_global_load_lds(
            (const __attribute__((address_space(1))) void*)ga,
            (__attribute__((address_space(3))) void*)(As[h] + i * 4096 + wv * 1024), 16, 0, 0);
      }
#pragma unroll
    for (int h = 0; h < NPB; ++h)
#pragma unroll
      for (int i = 0; i < 2; ++i) {
        const bf16* gb = Bt + h * bOff + (size_t)(n0 + i * 64 + grow) * ldb + k0 + gcol;
        __builtin_amdgcn_global_load_lds(
            (const __attribute__((address_space(1))) void*)gb,
            (__attribute__((address_space(3))) void*)(Bs[h] + i * 4096 + wv * 1024), 16, 0, 0);
      }
    __syncthreads();
    short8v ah[4], al[4], bh[4], bl[4];
#pragma unroll
    for (int mi = 0; mi < 4; ++mi) {
      int o = (wr * 64 + mi * 16 + row16) * 64 + kg * 16;
      ah[mi] = *(const short8v*)(As[0] + o);
      if (TERMS >= 3) al[mi] = *(const short8v*)(As[NPA - 1] + o);
    }
#pragma unroll
    for (int ni = 0; ni < 4; ++ni) {
      int o = (wc * 64 + ni * 16 + row16) * 64 + kg * 16;
      bh[ni] = *(const short8v*)(Bs[0] + o);
      if (TERMS >= 2) bl[ni] = *(const short8v*)(Bs[NPB - 1] + o);
    }
#pragma unroll
    for (int mi = 0; mi < 4; ++mi)
#pragma unroll
      for (int ni = 0; ni < 4; ++ni) {
        if (TERMS >= 2)
          acc[mi][ni] = __builtin_amdgcn_mfma_f32_16x16x32_bf16(ah[mi], bl[ni], acc[mi][ni], 0, 0, 0);
        if (TERMS >= 3)
          acc[mi][ni] = __builtin_amdgcn_mfma_f32_16x16x32_bf16(al[mi], bh[ni], acc[mi][ni], 0, 0, 0);
        acc[mi][ni] = __builtin_amdgcn_mfma_f32_16x16x32_bf16(ah[mi], bh[ni], acc[mi][ni], 0, 0, 0);
      }
    __syncthreads();
  }

  float invc = 1.0f;
  if (EPI == ME_SCALE || EPI == ME_SOFT || EPI == ME_SMAT) invc = 1.0f / cptr[0];
  bf16* Cb = (bf16*)Cv;
  float* Cf = (float*)Cv;
#pragma unroll
  for (int ni = 0; ni < 4; ++ni) {
    int col = n0 + wc * 64 + ni * 16 + row16;
    const bool colok = col < N;
    float bv = 0.0f;
    if ((EPI == ME_RELU || EPI == ME_SCALE || EPI == ME_SIG || EPI == ME_LIN) && colok)
      bv = bias[col];
    float dgv = 0.0f;
    if (EPI == ME_SOFT && colok) dgv = Dg[nb * 640 + col];
#pragma unroll
    for (int mi = 0; mi < 4; ++mi) {
      int rowb = m0 + wr * 64 + mi * 16 + kg * 4;
#pragma unroll
      for (int r = 0; r < 4; ++r) {
        int row = rowb + r;
        float v = acc[mi][ni][r];
        if (EPI == ME_RELU) {
          if (colok) {
            float o = fmaxf(v + bv, 0.0f);
            size_t ci = (size_t)row * ldc + col;
            if (WLO) {
              bf16 h, l; split2(o, h, l);
              Cb[ci] = h; Cb[ci + cOff] = l;
            } else {
              Cb[ci] = __float2bfloat16(o);
            }
          }
        } else if (EPI == ME_LIN) {
          if (colok && row < Rc) Cf[(size_t)row * ldc + col] = v + bv;
        } else if (EPI == ME_SCALE) {
          if (colok) Cf[(size_t)row * ldc + col] = (v + bv) * invc;
        } else if (EPI == ME_SIG) {
          if (colok) {
            int rl = row - nb * bRow;
            if (rl < Rc && rl >= 0)
              Cf[(size_t)col * NLR + (size_t)nb * L_LOC + r0 + rl] = sigf(v + bv);
          }
        } else if (EPI == ME_Y) {
          if (colok) {
            size_t e = (size_t)row * lde + col;
            Cf[(size_t)row * ldc + col] = v;
            Zp[(size_t)row * 640 + col] = __float2bfloat16(softf(v, E1[e]));
          }
        } else if (EPI == ME_SOFT) {
          if (colok) {
            size_t e = (size_t)row * lde + col;
            float zin = __bfloat162float(Zp[(size_t)row * 640 + col]);
            float v2 = v + zin * dgv + E1[e] * invc;
            Cb[(size_t)row * ldc + col] = __float2bfloat16(softf(v2, E2[e]));
          }
        } else if (EPI == ME_XP) {
          int rl = row - nb * bRow;
          if (colok && rl < Rc && rl >= 0) {
            size_t g = (size_t)col * NLR + (size_t)nb * L_LOC + r0 + rl;
            Cf[g] = fminf(fmaxf(v, 0.0f), 1.0f) * E1[g];
          }
        } else { // ME_SMAT: split S with zeroed diag; diag -> fp32 Dg
          float o = (row < 624 && col < 624) ? ((row == col ? 1.0f : 0.0f) - v * invc) : 0.0f;
          if (row == col && row < 624) { Dg[col] = o; o = 0.0f; }
          bf16 h, l; split2(o, h, l);
          size_t ci = (size_t)row * ldc + col;
          Cb[ci] = h; Cb[ci + cOff] = l;
        }
      }
    }
  }
}

static void mgemm(hipStream_t st, int EPI, int terms, int wlo,
                  const bf16* A, int lda, size_t aOff,
                  const bf16* B0, const bf16* B1, int ldb, size_t bOff,
                  void* C, int ldc, size_t cOff,
                  bf16* Zp, float* Dg,
                  const float* bias, const float* E1, const float* E2, int lde,
                  const float* cptr, int bRow, int Rc, int r0,
                  int Mp, int N, int K)
{
  dim3 grid(Mp / 128, (N + 127) / 128), blk(256);
#define MG(ep, tm, wl) mgemm_k<ep, tm, wl><<<grid, blk, 0, st>>>(A, lda, aOff, B0, B1, ldb, bOff, C, ldc, cOff, Zp, Dg, bias, E1, E2, lde, cptr, bRow, Rc, r0, N, K)
  if (EPI == ME_RELU && terms == 1 && !wlo) { MG(ME_RELU, 1, 0); }
  else if (EPI == ME_RELU && terms == 1)    { MG(ME_RELU, 1, 1); }
  else if (EPI == ME_RELU)                  { MG(ME_RELU, 3, 1); }
  else if (EPI == ME_LIN)                   { MG(ME_LIN, 3, 0); }
  else if (EPI == ME_SCALE)                 { MG(ME_SCALE, 3, 0); }
  else if (EPI == ME_SIG)                   { MG(ME_SIG, 1, 0); }
  else if (EPI == ME_Y)                     { MG(ME_Y, 3, 0); }
  else if (EPI == ME_SOFT)                  { MG(ME_SOFT, 1, 0); }   // diag-compensated
  else if (EPI == ME_XP)                    { MG(ME_XP, 2, 0); }
  else                                      { MG(ME_SMAT, 3, 0); }
#undef MG
}

// ================= small kernels ==============================================
struct WTable {
  const float* src[NW];
  bf16* dst[NW];
  int K[NW], N[NW], Kp[NW], Np[NW];
  long long loOff[NW];
  int base[NW + 1];
};

__global__ void wtransall_k(WTable w) {
  int idx = blockIdx.x * 256 + threadIdx.x;
  if (idx >= w.base[NW]) return;
  int s = 0;
  while (s < NW - 1 && idx >= w.base[s + 1]) ++s;
  int li = idx - w.base[s];
  int Kp = w.Kp[s];
  int n = li / Kp, k = li - n * Kp;
  float v = (n < w.N[s] && k < w.K[s]) ? w.src[s][(size_t)k * w.N[s] + n] : 0.0f;
  bf16 h, l; split2(v, h, l);
  w.dst[s][li] = h;
  w.dst[s][li + w.loOff[s]] = l;
}

// ext rows (stride-8 unfold) -> split bf16 [2pl][256 rows][256], pad rows zero
__global__ void extb_k(const float* __restrict__ img, bf16* __restrict__ dst) {
  int idx = blockIdx.x * 256 + threadIdx.x;   // 256*256
  int row = idx >> 8, p = idx & 255;
  float v = 0.0f;
  if (row < 224) {
    int n = row / 112, e = row - n * 112;
    int l1 = 2 * e, i1 = l1 / 15, j1 = l1 - i1 * 15;
    v = img[n * 16384 + (8 * i1 + (p >> 4)) * 128 + 8 * j1 + (p & 15)];
  }
  bf16 h, l; split2(v, h, l);
  dst[idx] = h; dst[idx + 65536] = l;
}

__global__ void rownorm224_k(float* sd) {
  int r = blockIdx.x, t = threadIdx.x;   // 224 blocks x 64 threads
  float v[4], s = 0.0f;
#pragma unroll
  for (int j = 0; j < 4; ++j) { v[j] = sd[r * 256 + t + 64 * j]; s += v[j] * v[j]; }
#pragma unroll
  for (int o = 1; o < 64; o <<= 1) s += __shfl_xor(s, o);
  float sc = 1.0f / fmaxf(sqrtf(s), 1e-12f);
#pragma unroll
  for (int j = 0; j < 4; ++j) sd[r * 256 + t + 64 * j] = v[j] * sc;
}

// ---- CBAM, multi-block ----
__global__ void meanmax_k(const float* __restrict__ sd, float* mv, float* xv) {
  int id = blockIdx.x * 256 + threadIdx.x;   // 512
  int n = id >> 8, ch = id & 255;
  float s = 0.0f, m = -INFINITY;
  for (int e = 0; e < 112; ++e) {
    float v = sd[(n * 112 + e) * 256 + ch];
    s += v; m = fmaxf(m, v);
  }
  mv[id] = s * (1.0f / 112.0f);
  xv[id] = m;
}

__global__ void cah_k(const float* __restrict__ mv, const float* __restrict__ xv,
                      const float* __restrict__ w1, float* hm, float* hx) {
  int id = blockIdx.x * 256 + threadIdx.x;   // 1024 (4 blocks)
  int n = id >> 9, o = id & 511;
  float sm = 0.0f, sx = 0.0f;
#pragma unroll 4
  for (int i = 0; i < 256; ++i) {
    float w = w1[i * 512 + o];
    sm = fmaf(mv[n * 256 + i], w, sm);
    sx = fmaf(xv[n * 256 + i], w, sx);
  }
  hm[id] = fmaxf(sm, 0.0f);
  hx[id] = fmaxf(sx, 0.0f);
}

__global__ void cao_k(const float* __restrict__ hm, const float* __restrict__ hx,
                      const float* __restrict__ w2, float* ca) {
  int id = blockIdx.x * 256 + threadIdx.x;   // 512 (2 blocks)
  int n = id >> 8, ch = id & 255;
  float s = 0.0f;
#pragma unroll 4
  for (int o = 0; o < 512; ++o)
    s = fmaf(hm[n * 512 + o] + hx[n * 512 + o], w2[o * 256 + ch], s);
  ca[id] = sigf(s);
}

// per-batch: channel-attend + spatial mean/max + 7x7 conv + scale into Dcat_f
__global__ void spatial_k(const float* __restrict__ sd, const float* __restrict__ ca,
                          const float* __restrict__ saw, float* __restrict__ Dcat) {
  __shared__ float smean[112], smax[112];
  const int n = blockIdx.x, t = threadIdx.x;   // 2 blocks x 128
  if (t < 112) {
    float sum = 0.0f, mx = -INFINITY;
    for (int ch = 0; ch < 256; ++ch) {
      float v = sd[(n * 112 + t) * 256 + ch] * ca[n * 256 + ch];
      Dcat[(size_t)n * 159744 + ch * 624 + 512 + t] = v;
      sum += v; mx = fmaxf(mx, v);
    }
    smean[t] = sum * (1.0f / 256.0f);
    smax[t] = mx;
  }
  __syncthreads();
  if (t < 112) {
    int h = t / 14, w = t % 14;
    float acc = 0.0f;
    for (int dh = 0; dh < 7; ++dh) {
      int hh = h + dh - 3; if (hh < 0 || hh >= 8) continue;
      for (int dw = 0; dw < 7; ++dw) {
        int ww = w + dw - 3; if (ww < 0 || ww >= 14) continue;
        int sp = hh * 14 + ww;
        acc += smean[sp] * saw[dh * 7 + dw] + smax[sp] * saw[49 + dh * 7 + dw];
      }
    }
    float sg = sigf(acc);
    for (int ch = 0; ch < 256; ++ch) Dcat[(size_t)n * 159744 + ch * 624 + 512 + t] *= sg;
  }
}

// Dict [256][512] + Dcat_f sd-part -> Db [n][2pl][256][640], DbT [n][2pl][640][256]
__global__ void dcatconv_k(const float* __restrict__ Dict, const float* __restrict__ Dc,
                           bf16* __restrict__ Db, bf16* __restrict__ DbT) {
  int idx = blockIdx.x * 256 + threadIdx.x;   // 2*256*640
  if (idx >= 327680) return;
  int n = idx / 163840, r = idx - n * 163840;
  int p = r / 640, a = r - p * 640;
  float v = 0.0f;
  if (a < 512)      v = Dict[p * 512 + a];
  else if (a < 624) v = Dc[(size_t)n * 159744 + p * 624 + a];
  bf16 h, l; split2(v, h, l);
  size_t base = (size_t)n * 327680;
  Db[base + p * 640 + a] = h;
  Db[base + 163840 + p * 640 + a] = l;
  DbT[base + (size_t)a * 256 + p] = h;
  DbT[base + 163840 + (size_t)a * 256 + p] = l;
}

// unfold for both batches into the stacked chunk buffer
__global__ void unfold_k(const float* __restrict__ img, bf16* __restrict__ uf,
                         int r0, int Rc, int bRowc, size_t pOff) {
  int bi = blockIdx.x;               // 0..2*Rc-1
  int nb = bi >= Rc;
  int rl = nb ? bi - Rc : bi;
  int row = nb * bRowc + rl;
  int p = threadIdx.x;
  int l = r0 + rl;
  int i0 = l / 113, j0 = l - i0 * 113;
  float v = img[nb * 16384 + (i0 + (p >> 4)) * 128 + j0 + (p & 15)];
  bf16 h, lo; split2(v, h, lo);
  size_t o = (size_t)row * 256 + p;
  uf[o] = h; uf[o + pOff] = lo;
}

// overlap-add fold + divide; 8 lanes per pixel (kh split), shfl reduce
__global__ void folddiv_k(const float* __restrict__ xpT, const float* __restrict__ wgT,
                          float* __restrict__ out) {
  int idx = blockIdx.x * 256 + threadIdx.x;  // 262144 = 32768 pixels * 8
  if (idx >= 262144) return;
  int g = idx & 7;
  int pix = idx >> 3;
  int n = pix >> 14, rem = pix & 16383;
  int i = rem >> 7, j = rem & 127;
  float num = 0.0f, den = 0.0f;
  int kh0 = (i - 112 > 0) ? i - 112 : 0;
  int kh1 = (i < 15) ? i : 15;
  int kw0 = (j - 112 > 0) ? j - 112 : 0;
  int kw1 = (j < 15) ? j : 15;
  for (int kh = kh0 + ((g - kh0) & 7); kh <= kh1; kh += 8)
    for (int kw = kw0; kw <= kw1; ++kw) {
      int l = (i - kh) * 113 + (j - kw);
      size_t base = (size_t)(kh * 16 + kw) * NLR + (size_t)n * L_LOC + l;
      num += xpT[base];
      den += wgT[base];
    }
#pragma unroll
  for (int o = 1; o < 8; o <<= 1) {
    num += __shfl_xor(num, o);
    den += __shfl_xor(den, o);
  }
  if (g == 0) out[pix] = num / den;
}

// ================= host orchestration ==========================================
struct Bufs {
  float *xp, *wg, *Dcat_f, *sd, *res;
  float *mv, *xv, *hm, *hx, *ca, *Dg;
  bf16 *Db, *DbT, *Sb;
  bf16 *extb, *sdh1, *sdh2, *sdh3;
  bf16 *uf, *h1, *h2, *z, *zn;
  float *thr, *y;
  size_t ufO, h2O;
  int R;
};

static void run_stage(hipStream_t st, const float* const* in, const float* img,
                      float* outimg, int pd0, int lam0,
                      bf16* const* WtPd, bf16* const* WtLam, bf16* const* WtW,
                      bf16* const* Ws, const Bufs& b)
{
  const float* cptr = in[2];
  const int BIG = 1 << 30;
  // --- adaptive dictionary pipeline via MFMA (TERMS=3 ~ fp32) ---
  extb_k<<<dim3(256), dim3(256), 0, st>>>(img, b.extb);
  mgemm(st, ME_RELU, 3, 1, b.extb, 256, 65536, Ws[0], Ws[0], 256, 512 * 256,
        b.sdh1, 512, 256 * 512, 0, 0, in[4], 0, 0, 0, cptr, BIG, 224, 0, 256, 512, 256);
  mgemm(st, ME_RELU, 3, 1, b.sdh1, 512, 256 * 512, Ws[1], Ws[1], 512, 1024 * 512,
        b.sdh2, 1024, 256 * 1024, 0, 0, in[6], 0, 0, 0, cptr, BIG, 224, 0, 256, 1024, 512);
  mgemm(st, ME_RELU, 3, 1, b.sdh2, 1024, 256 * 1024, Ws[2], Ws[2], 1024, 512 * 1024,
        b.sdh3, 512, 256 * 512, 0, 0, in[8], 0, 0, 0, cptr, BIG, 224, 0, 256, 512, 1024);
  mgemm(st, ME_LIN, 3, 0, b.sdh3, 512, 256 * 512, Ws[3], Ws[3], 512, 256 * 512,
        b.sd, 256, 0, 0, 0, in[10], 0, 0, 0, cptr, BIG, 224, 0, 256, 256, 512);
  rownorm224_k<<<dim3(224), dim3(64), 0, st>>>(b.sd);
  // CBAM, multi-block
  meanmax_k<<<dim3(2), dim3(256), 0, st>>>(b.sd, b.mv, b.xv);
  cah_k<<<dim3(4), dim3(256), 0, st>>>(b.mv, b.xv, in[41], b.hm, b.hx);
  cao_k<<<dim3(2), dim3(256), 0, st>>>(b.hm, b.hx, in[42], b.ca);
  spatial_k<<<dim3(2), dim3(128), 0, st>>>(b.sd, b.ca, in[43], b.Dcat_f);
  dcatconv_k<<<dim3(1280), dim3(256), 0, st>>>(in[1], b.Dcat_f, b.Db, b.DbT);
  // --- S = I - D^T D / c via split MFMA; diag -> fp32 Dg, bf16 planes zero-diag
  for (int n = 0; n < NB; ++n) {
    const bf16* Dt = b.DbT + (size_t)n * 327680;
    mgemm(st, ME_SMAT, 3, 0, Dt, 256, 163840, Dt, Dt, 256, 163840,
          b.Sb + (size_t)n * 819200, 640, 409600, 0, b.Dg + n * 640,
          0, 0, 0, 0, cptr, BIG, 624, 0, 640, 640, 256);
  }

  // --- stacked both-batch chunks ---
  for (int r0 = 0; r0 < L_LOC; r0 += b.R) {
    int Rc = L_LOC - r0; if (Rc > b.R) Rc = b.R;
    int bRowc = ((Rc + 127) / 128) * 128;
    int Mp = 2 * bRowc;
    unfold_k<<<dim3(2 * Rc), dim3(256), 0, st>>>(img, b.uf, r0, Rc, bRowc, b.ufO);
    // pd MLP -> thr[:, :512]
    mgemm(st, ME_RELU, 1, 0, b.uf, 256, b.ufO, WtPd[0], WtPd[0], 256, 1024 * 256,
          b.h1, 1024, 0, 0, 0, in[pd0 + 1], 0, 0, 0, cptr, bRowc, Rc, r0, Mp, 1024, 256);
    mgemm(st, ME_RELU, 1, 1, b.h1, 1024, 0, WtPd[1], WtPd[1], 1024, 512 * 1024,
          b.h2, 512, b.h2O, 0, 0, in[pd0 + 3], 0, 0, 0, cptr, bRowc, Rc, r0, Mp, 512, 1024);
    mgemm(st, ME_SCALE, 3, 0, b.h2, 512, b.h2O, WtPd[2], WtPd[2], 512, 512 * 512,
          b.thr, 640, 0, 0, 0, in[pd0 + 5], 0, 0, 0, cptr, bRowc, Rc, r0, Mp, 512, 512);
    // lam MLP -> thr[:, 512:624]
    mgemm(st, ME_RELU, 1, 0, b.uf, 256, b.ufO, WtLam[0], WtLam[0], 256, 1024 * 256,
          b.h1, 1024, 0, 0, 0, in[lam0 + 1], 0, 0, 0, cptr, bRowc, Rc, r0, Mp, 1024, 256);
    mgemm(st, ME_RELU, 1, 1, b.h1, 1024, 0, WtLam[1], WtLam[1], 1024, 512 * 1024,
          b.h2, 512, b.h2O, 0, 0, in[lam0 + 3], 0, 0, 0, cptr, bRowc, Rc, r0, Mp, 512, 1024);
    mgemm(st, ME_SCALE, 3, 0, b.h2, 512, b.h2O, WtLam[2], WtLam[2], 512, 128 * 512,
          b.thr + 512, 640, 0, 0, 0, in[lam0 + 5], 0, 0, 0, cptr, bRowc, Rc, r0, Mp, 112, 512);
    // w MLP -> WgT (transposed, sigmoid)
    mgemm(st, ME_RELU, 1, 0, b.uf, 256, b.ufO, WtW[0], WtW[0], 256, 1024 * 256,
          b.h1, 1024, 0, 0, 0, in[36], 0, 0, 0, cptr, bRowc, Rc, r0, Mp, 1024, 256);
    mgemm(st, ME_RELU, 1, 1, b.h1, 1024, 0, WtW[1], WtW[1], 1024, 512 * 1024,
          b.h2, 512, b.h2O, 0, 0, in[38], 0, 0, 0, cptr, bRowc, Rc, r0, Mp, 512, 1024);
    mgemm(st, ME_SIG, 1, 0, b.h2, 512, b.h2O, WtW[2], WtW[2], 512, 256 * 512,
          b.wg, 0, 0, 0, 0, in[40], 0, 0, 0, cptr, bRowc, Rc, r0, Mp, 256, 512);
    // y = uf @ Dcat, fused z0 = soft(y, thr)
    mgemm(st, ME_Y, 3, 0, b.uf, 256, b.ufO, b.DbT, b.DbT + 327680, 256, 163840,
          b.y, 640, 0, b.z, 0, 0, b.thr, 0, 640, cptr, bRowc, Rc, r0, Mp, 624, 256);
    // LISTA iterations: z@S_offdiag (1 MFMA term) + exact diag in epilogue
    bf16* zi = b.z; bf16* zo = b.zn;
    for (int it = 0; it < 5; ++it) {
      mgemm(st, ME_SOFT, 1, 0, zi, 640, 0, b.Sb, b.Sb + 819200, 640, 409600,
            zo, 640, 0, zi, b.Dg, 0, b.y, b.thr, 640, cptr, bRowc, Rc, r0, Mp, 624, 640);
      bf16* tmp = zi; zi = zo; zo = tmp;
    }
    // x_pred -> xpT (transposed, clip * Wg), TERMS=2
    mgemm(st, ME_XP, 2, 0, zi, 640, 0, b.Db, b.Db + 327680, 640, 163840,
          b.xp, 0, 0, 0, 0, 0, b.wg, 0, 0, cptr, bRowc, Rc, r0, Mp, 256, 640);
  }
  folddiv_k<<<dim3(1024), dim3(256), 0, st>>>(b.xp, b.wg, outimg);
}

extern "C" void kernel_launch(void* const* d_in, const int* in_sizes, int n_in,
                              void* d_out, int out_size, void* d_ws, size_t ws_size,
                              hipStream_t stream)
{
  (void)in_sizes; (void)n_in; (void)out_size;
  const float* const* in = (const float* const*)d_in;
  char* base = (char*)d_ws;
  size_t off = 0;
  auto allocf = [&](size_t nelem) -> float* {
    float* p = (float*)(base + off);
    off += ((nelem * 4 + 255) / 256) * 256;
    return p;
  };
  auto allocb2 = [&](size_t nelem) -> bf16* {  // hi+lo planes
    bf16* p = (bf16*)(base + off);
    off += ((nelem * 2 * 2 + 255) / 256) * 256;
    return p;
  };
  auto allocb1 = [&](size_t nelem) -> bf16* {  // single plane
    bf16* p = (bf16*)(base + off);
    off += ((nelem * 2 + 255) / 256) * 256;
    return p;
  };
  Bufs b;
  b.xp = allocf((size_t)NLR * 256);   // transposed [256][NLR]
  b.wg = allocf((size_t)NLR * 256);   // transposed [256][NLR]
  b.Dcat_f = allocf(2 * 256 * 624);
  b.sd = allocf(224 * 256);
  b.res = allocf(2 * 16384);
  b.mv = allocf(512); b.xv = allocf(512);
  b.hm = allocf(1024); b.hx = allocf(1024);
  b.ca = allocf(512);
  b.Dg = allocf(2 * 640);
  b.Db = allocb2(2 * 163840);
  b.DbT = allocb2(2 * 163840);
  b.Sb = allocb2(2 * 409600);
  b.extb = allocb2(256 * 256);
  b.sdh1 = allocb2(256 * 512);
  b.sdh2 = allocb2(256 * 1024);
  b.sdh3 = allocb2(256 * 512);

  // transposed split-bf16 weights (single merged launch)
  bf16 *Wa[3], *Wp[3], *Wb[3], *Wq[3], *Ww[3], *Ws[4];
  WTable wt;
  int ne = 0, tot = 0;
  auto addw = [&](const float* src, bf16* dst, int K, int N, int Kp, int Np) {
    wt.src[ne] = src; wt.dst[ne] = dst;
    wt.K[ne] = K; wt.N[ne] = N; wt.Kp[ne] = Kp; wt.Np[ne] = Np;
    wt.loOff[ne] = (long long)Np * Kp; wt.base[ne] = tot;
    tot += Np * Kp; ++ne;
  };
  int sdK[4] = {256, 512, 1024, 512}, sdN[4] = {512, 1024, 512, 256}, sdIdx[4] = {3, 5, 7, 9};
  for (int i = 0; i < 4; ++i) {
    Ws[i] = allocb2((size_t)sdN[i] * sdK[i]);
    addw(in[sdIdx[i]], Ws[i], sdK[i], sdN[i], sdK[i], sdN[i]);
  }
  struct WD { bf16** slot; int idx, K, N, Kp, Np; };
  WD wd[15] = {
    {&Wa[0], 11, 256, 1024, 256, 1024}, {&Wa[1], 13, 1024, 512, 1024, 512}, {&Wa[2], 15, 512, 112, 512, 128},
    {&Wp[0], 17, 256, 1024, 256, 1024}, {&Wp[1], 19, 1024, 512, 1024, 512}, {&Wp[2], 21, 512, 512, 512, 512},
    {&Wb[0], 23, 256, 1024, 256, 1024}, {&Wb[1], 25, 1024, 512, 1024, 512}, {&Wb[2], 27, 512, 112, 512, 128},
    {&Wq[0], 29, 256, 1024, 256, 1024}, {&Wq[1], 31, 1024, 512, 1024, 512}, {&Wq[2], 33, 512, 512, 512, 512},
    {&Ww[0], 35, 256, 1024, 256, 1024}, {&Ww[1], 37, 1024, 512, 1024, 512}, {&Ww[2], 39, 512, 256, 512, 256},
  };
  for (int i = 0; i < 15; ++i) {
    *wd[i].slot = allocb2((size_t)wd[i].Np * wd[i].Kp);
    addw(in[wd[i].idx], *wd[i].slot, wd[i].K, wd[i].N, wd[i].Kp, wd[i].Np);
  }
  wt.base[NW] = tot;
  wtransall_k<<<dim3((tot + 255) / 256), dim3(256), 0, stream>>>(wt);

  // chunk size (per batch-row bytes: uf 1024 + h1 2048 + h2 2048 + z 1280 +
  // zn 1280 + thr 2560 + y 2560 = 12800; chunk holds 2R rows)
  long long avail = (long long)ws_size - (long long)off - (1 << 20);
  long long perrow2 = 2LL * (12800 + 64);
  int R = 12800;
  if (avail / perrow2 < 12800) R = (int)(avail / perrow2);
  R &= ~127;
  if (R < 128) R = 128;
  b.R = R;
  size_t rows2 = (size_t)2 * R;
  b.uf = allocb2(rows2 * 256);  b.ufO = rows2 * 256;
  b.h1 = allocb1(rows2 * 1024);                       // hi only, reused 3x
  b.h2 = allocb2(rows2 * 512);  b.h2O = rows2 * 512;  // hi+lo (L3 TERMS=3)
  b.z = allocb1(rows2 * 640);
  b.zn = allocb1(rows2 * 640);
  b.thr = allocf(rows2 * 640);
  b.y = allocf(rows2 * 640);

  // stage 1: pd = p*(17), lam = a*(11); stage 2: pd = q*(29), lam = b*(23)
  run_stage(stream, in, in[0], b.res, 17, 11, Wp, Wa, Ww, Ws, b);
  run_stage(stream, in, b.res, (float*)d_out, 29, 23, Wq, Wb, Ww, Ws, b);
}

// Round 11
// 3133.608 us; speedup vs baseline: 1.2270x; 1.0034x over previous
//
#include <hip/hip_runtime.h>
#include <hip/hip_bf16.h>
#include <math.h>

#define L_LOC 12769              // 113*113 sliding-window positions
#define NB 2
#define NLR (NB * L_LOC)
#define NW 19

typedef short short8v __attribute__((ext_vector_type(8)));
typedef float f32x4 __attribute__((ext_vector_type(4)));
typedef __hip_bfloat16 bf16;

__device__ __forceinline__ float softf(float x, float l) {
  float a = fmaxf(fabsf(x) - l, 0.0f);
  return x > 0.0f ? a : (x < 0.0f ? -a : 0.0f);
}
__device__ __forceinline__ float sigf(float x) { return 1.0f / (1.0f + expf(-x)); }
__device__ __forceinline__ void split2(float v, bf16& h, bf16& l) {
  h = __float2bfloat16(v);
  l = __float2bfloat16(v - __bfloat162float(h));
}

// ================= split-bf16 MFMA GEMM ========================================
// A: hi plane at A, lo at A+aOff. B per batch (B0/B1 by m0>=bRow), lo at +bOff.
// TERMS=3: Ah*Bh + Ah*Bl + Al*Bh.  TERMS=2: Ah*(Bh+Bl).  TERMS=1: Ah*Bh.
// Grid: x = N-blocks (so blocks sharing an A-panel are dispatch-adjacent -> L2/L3
// absorb A re-reads), y = M-blocks.
enum { ME_RELU = 0, ME_SCALE = 1, ME_SIG = 2, ME_Y = 3, ME_SOFT = 4, ME_XP = 5,
       ME_SMAT = 6, ME_LIN = 7 };

template <int EPI, int TERMS, int WLO>
__global__ __launch_bounds__(256) void mgemm_k(
    const bf16* __restrict__ A, int lda, size_t aOff,
    const bf16* __restrict__ B0, const bf16* __restrict__ B1, int ldb, size_t bOff,
    void* __restrict__ Cv, int ldc, size_t cOff,
    bf16* __restrict__ Zp,
    const float* __restrict__ bias,
    const void* __restrict__ E1, const void* __restrict__ E2, int lde,
    const float* __restrict__ cptr, int bRow, int Rc, int r0, int N, int K)
{
  const int NPA = (TERMS >= 3) ? 2 : 1;
  const int NPB = (TERMS >= 2) ? 2 : 1;
  __shared__ char As[(TERMS >= 3) ? 2 : 1][8192];   // [pl][128 rows][32 k] bf16
  __shared__ char Bs[(TERMS >= 2) ? 2 : 1][8192];
  const int t = threadIdx.x;
  const int lane = t & 63, wv = t >> 6;
  const int wr = wv >> 1, wc = wv & 1;
  const int m0 = blockIdx.y * 128, n0 = blockIdx.x * 128;
  const int nb = (m0 >= bRow) ? 1 : 0;
  const bf16* __restrict__ Bt = nb ? B1 : B0;
  const int row16 = lane & 15, kg = lane >> 4;
  const int grow = t >> 2;
  const int gcol = (t & 3) * 8;
  f32x4 acc[4][4];
#pragma unroll
  for (int i = 0; i < 4; ++i)
#pragma unroll
    for (int j = 0; j < 4; ++j) { acc[i][j][0] = 0.f; acc[i][j][1] = 0.f; acc[i][j][2] = 0.f; acc[i][j][3] = 0.f; }

  for (int k0 = 0; k0 < K; k0 += 32) {
#pragma unroll
    for (int h = 0; h < NPA; ++h)
#pragma unroll
      for (int i = 0; i < 2; ++i) {
        const bf16* ga = A + h * aOff + (size_t)(m0 + i * 64 + grow) * lda + k0 + gcol;
        __builtin_amdgcn_global_load_lds(
            (const __attribute__((address_space(1))) void*)ga,
            (__attribute__((address_space(3))) void*)(As[h] + i * 4096 + wv * 1024), 16, 0, 0);
      }
#pragma unroll
    for (int h = 0; h < NPB; ++h)
#pragma unroll
      for (int i = 0; i < 2; ++i) {
        const bf16* gb = Bt + h * bOff + (size_t)(n0 + i * 64 + grow) * ldb + k0 + gcol;
        __builtin_amdgcn_global_load_lds(
            (const __attribute__((address_space(1))) void*)gb,
            (__attribute__((address_space(3))) void*)(Bs[h] + i * 4096 + wv * 1024), 16, 0, 0);
      }
    __syncthreads();
    short8v ah[4], al[4], bh[4], bl[4];
#pragma unroll
    for (int mi = 0; mi < 4; ++mi) {
      int o = (wr * 64 + mi * 16 + row16) * 64 + kg * 16;
      ah[mi] = *(const short8v*)(As[0] + o);
      if (TERMS >= 3) al[mi] = *(const short8v*)(As[NPA - 1] + o);
    }
#pragma unroll
    for (int ni = 0; ni < 4; ++ni) {
      int o = (wc * 64 + ni * 16 + row16) * 64 + kg * 16;
      bh[ni] = *(const short8v*)(Bs[0] + o);
      if (TERMS >= 2) bl[ni] = *(const short8v*)(Bs[NPB - 1] + o);
    }
#pragma unroll
    for (int mi = 0; mi < 4; ++mi)
#pragma unroll
      for (int ni = 0; ni < 4; ++ni) {
        if (TERMS >= 2)
          acc[mi][ni] = __builtin_amdgcn_mfma_f32_16x16x32_bf16(ah[mi], bl[ni], acc[mi][ni], 0, 0, 0);
        if (TERMS >= 3)
          acc[mi][ni] = __builtin_amdgcn_mfma_f32_16x16x32_bf16(al[mi], bh[ni], acc[mi][ni], 0, 0, 0);
        acc[mi][ni] = __builtin_amdgcn_mfma_f32_16x16x32_bf16(ah[mi], bh[ni], acc[mi][ni], 0, 0, 0);
      }
    __syncthreads();
  }

  float invc = 1.0f;
  if (EPI == ME_SCALE || EPI == ME_SOFT || EPI == ME_SMAT) invc = 1.0f / cptr[0];
  bf16* Cb = (bf16*)Cv;
  float* Cf = (float*)Cv;
  const bf16* E1b = (const bf16*)E1;
  const bf16* E2b = (const bf16*)E2;
  const float* E1f = (const float*)E1;
#pragma unroll
  for (int ni = 0; ni < 4; ++ni) {
    int col = n0 + wc * 64 + ni * 16 + row16;
    const bool colok = col < N;
    float bv = 0.0f;
    if ((EPI == ME_RELU || EPI == ME_SCALE || EPI == ME_SIG || EPI == ME_LIN) && colok)
      bv = bias[col];
#pragma unroll
    for (int mi = 0; mi < 4; ++mi) {
      int rowb = m0 + wr * 64 + mi * 16 + kg * 4;
#pragma unroll
      for (int r = 0; r < 4; ++r) {
        int row = rowb + r;
        float v = acc[mi][ni][r];
        if (EPI == ME_RELU) {
          if (colok) {
            float o = fmaxf(v + bv, 0.0f);
            size_t ci = (size_t)row * ldc + col;
            if (WLO) {
              bf16 h, l; split2(o, h, l);
              Cb[ci] = h; Cb[ci + cOff] = l;
            } else {
              Cb[ci] = __float2bfloat16(o);
            }
          }
        } else if (EPI == ME_LIN) {
          if (colok && row < Rc) Cf[(size_t)row * ldc + col] = v + bv;
        } else if (EPI == ME_SCALE) {
          if (colok) Cb[(size_t)row * ldc + col] = __float2bfloat16((v + bv) * invc);
        } else if (EPI == ME_SIG) {
          if (colok) {
            int rl = row - nb * bRow;
            if (rl < Rc && rl >= 0)
              Cf[(size_t)col * NLR + (size_t)nb * L_LOC + r0 + rl] = sigf(v + bv);
          }
        } else if (EPI == ME_Y) {
          if (colok) {
            size_t e = (size_t)row * lde + col;
            Cb[(size_t)row * ldc + col] = __float2bfloat16(v);       // y (bf16)
            float tv = __bfloat162float(E1b[e]);                     // thr
            Zp[(size_t)row * 640 + col] = __float2bfloat16(softf(v, tv));
          }
        } else if (EPI == ME_SOFT) {
          if (colok) {
            size_t e = (size_t)row * lde + col;
            float yv = __bfloat162float(E1b[e]);                     // y
            float tv = __bfloat162float(E2b[e]);                     // thr
            Cb[(size_t)row * ldc + col] = __float2bfloat16(softf(v + yv * invc, tv));
          }
        } else if (EPI == ME_XP) {
          int rl = row - nb * bRow;
          if (colok && rl < Rc && rl >= 0) {
            size_t g = (size_t)col * NLR + (size_t)nb * L_LOC + r0 + rl;
            Cf[g] = fminf(fmaxf(v, 0.0f), 1.0f) * E1f[g];
          }
        } else { // ME_SMAT: write full split-bf16 S, zero pads
          float o = (row < 624 && col < 624) ? ((row == col ? 1.0f : 0.0f) - v * invc) : 0.0f;
          bf16 h, l; split2(o, h, l);
          size_t ci = (size_t)row * ldc + col;
          Cb[ci] = h; Cb[ci + cOff] = l;
        }
      }
    }
  }
}

static void mgemm(hipStream_t st, int EPI, int terms, int wlo,
                  const bf16* A, int lda, size_t aOff,
                  const bf16* B0, const bf16* B1, int ldb, size_t bOff,
                  void* C, int ldc, size_t cOff,
                  bf16* Zp,
                  const float* bias, const void* E1, const void* E2, int lde,
                  const float* cptr, int bRow, int Rc, int r0,
                  int Mp, int N, int K)
{
  dim3 grid((N + 127) / 128, Mp / 128), blk(256);
#define MG(ep, tm, wl) mgemm_k<ep, tm, wl><<<grid, blk, 0, st>>>(A, lda, aOff, B0, B1, ldb, bOff, C, ldc, cOff, Zp, bias, E1, E2, lde, cptr, bRow, Rc, r0, N, K)
  if (EPI == ME_RELU && terms == 1 && !wlo) { MG(ME_RELU, 1, 0); }
  else if (EPI == ME_RELU && terms == 1)    { MG(ME_RELU, 1, 1); }
  else if (EPI == ME_RELU)                  { MG(ME_RELU, 3, 1); }
  else if (EPI == ME_LIN)                   { MG(ME_LIN, 3, 0); }
  else if (EPI == ME_SCALE)                 { MG(ME_SCALE, 3, 0); }
  else if (EPI == ME_SIG)                   { MG(ME_SIG, 1, 0); }
  else if (EPI == ME_Y)                     { MG(ME_Y, 3, 0); }
  else if (EPI == ME_SOFT)                  { MG(ME_SOFT, 2, 0); }
  else if (EPI == ME_XP)                    { MG(ME_XP, 2, 0); }
  else                                      { MG(ME_SMAT, 3, 0); }
#undef MG
}

// ================= small kernels ==============================================
struct WTable {
  const float* src[NW];
  bf16* dst[NW];
  int K[NW], N[NW], Kp[NW], Np[NW];
  long long loOff[NW];
  int base[NW + 1];
};

__global__ void wtransall_k(WTable w) {
  int idx = blockIdx.x * 256 + threadIdx.x;
  if (idx >= w.base[NW]) return;
  int s = 0;
  while (s < NW - 1 && idx >= w.base[s + 1]) ++s;
  int li = idx - w.base[s];
  int Kp = w.Kp[s];
  int n = li / Kp, k = li - n * Kp;
  float v = (n < w.N[s] && k < w.K[s]) ? w.src[s][(size_t)k * w.N[s] + n] : 0.0f;
  bf16 h, l; split2(v, h, l);
  w.dst[s][li] = h;
  w.dst[s][li + w.loOff[s]] = l;
}

// ext rows (stride-8 unfold) -> split bf16 [2pl][256 rows][256], pad rows zero
__global__ void extb_k(const float* __restrict__ img, bf16* __restrict__ dst) {
  int idx = blockIdx.x * 256 + threadIdx.x;   // 256*256
  int row = idx >> 8, p = idx & 255;
  float v = 0.0f;
  if (row < 224) {
    int n = row / 112, e = row - n * 112;
    int l1 = 2 * e, i1 = l1 / 15, j1 = l1 - i1 * 15;
    v = img[n * 16384 + (8 * i1 + (p >> 4)) * 128 + 8 * j1 + (p & 15)];
  }
  bf16 h, l; split2(v, h, l);
  dst[idx] = h; dst[idx + 65536] = l;
}

__global__ void rownorm224_k(float* sd) {
  int r = blockIdx.x, t = threadIdx.x;   // 224 blocks x 64 threads
  float v[4], s = 0.0f;
#pragma unroll
  for (int j = 0; j < 4; ++j) { v[j] = sd[r * 256 + t + 64 * j]; s += v[j] * v[j]; }
#pragma unroll
  for (int o = 1; o < 64; o <<= 1) s += __shfl_xor(s, o);
  float sc = 1.0f / fmaxf(sqrtf(s), 1e-12f);
#pragma unroll
  for (int j = 0; j < 4; ++j) sd[r * 256 + t + 64 * j] = v[j] * sc;
}

// ---- CBAM, multi-block ----
__global__ void meanmax_k(const float* __restrict__ sd, float* mv, float* xv) {
  int id = blockIdx.x * 256 + threadIdx.x;   // 512
  int n = id >> 8, ch = id & 255;
  float s = 0.0f, m = -INFINITY;
  for (int e = 0; e < 112; ++e) {
    float v = sd[(n * 112 + e) * 256 + ch];
    s += v; m = fmaxf(m, v);
  }
  mv[id] = s * (1.0f / 112.0f);
  xv[id] = m;
}

__global__ void cah_k(const float* __restrict__ mv, const float* __restrict__ xv,
                      const float* __restrict__ w1, float* hm, float* hx) {
  int id = blockIdx.x * 256 + threadIdx.x;   // 1024 (4 blocks)
  int n = id >> 9, o = id & 511;
  float sm = 0.0f, sx = 0.0f;
#pragma unroll 4
  for (int i = 0; i < 256; ++i) {
    float w = w1[i * 512 + o];
    sm = fmaf(mv[n * 256 + i], w, sm);
    sx = fmaf(xv[n * 256 + i], w, sx);
  }
  hm[id] = fmaxf(sm, 0.0f);
  hx[id] = fmaxf(sx, 0.0f);
}

__global__ void cao_k(const float* __restrict__ hm, const float* __restrict__ hx,
                      const float* __restrict__ w2, float* ca) {
  int id = blockIdx.x * 256 + threadIdx.x;   // 512 (2 blocks)
  int n = id >> 8, ch = id & 255;
  float s = 0.0f;
#pragma unroll 4
  for (int o = 0; o < 512; ++o)
    s = fmaf(hm[n * 512 + o] + hx[n * 512 + o], w2[o * 256 + ch], s);
  ca[id] = sigf(s);
}

// per-batch CBAM spatial: coalesced (lane = channel), wave handles 28 s-rows
__global__ __launch_bounds__(256) void spatial_k(
    const float* __restrict__ sd, const float* __restrict__ ca,
    const float* __restrict__ saw, float* __restrict__ Dcat)
{
  __shared__ float smean[112], smax[112], sa[112];
  const int n = blockIdx.x;   // 2 blocks
  const int t = threadIdx.x, lane = t & 63, w = t >> 6;
  float cav[4];
#pragma unroll
  for (int c = 0; c < 4; ++c) cav[c] = ca[n * 256 + lane + 64 * c];
  for (int s = w * 28; s < w * 28 + 28; ++s) {
    float sum = 0.0f, mx = -INFINITY;
#pragma unroll
    for (int c = 0; c < 4; ++c) {
      int ch = lane + 64 * c;
      float v = sd[(n * 112 + s) * 256 + ch] * cav[c];
      Dcat[(size_t)n * 159744 + ch * 624 + 512 + s] = v;
      sum += v; mx = fmaxf(mx, v);
    }
#pragma unroll
    for (int o = 1; o < 64; o <<= 1) {
      sum += __shfl_xor(sum, o);
      mx = fmaxf(mx, __shfl_xor(mx, o));
    }
    if (lane == 0) { smean[s] = sum * (1.0f / 256.0f); smax[s] = mx; }
  }
  __syncthreads();
  if (t < 112) {
    int h = t / 14, wd = t % 14;
    float acc = 0.0f;
    for (int dh = 0; dh < 7; ++dh) {
      int hh = h + dh - 3; if (hh < 0 || hh >= 8) continue;
      for (int dw = 0; dw < 7; ++dw) {
        int ww = wd + dw - 3; if (ww < 0 || ww >= 14) continue;
        int sp = hh * 14 + ww;
        acc += smean[sp] * saw[dh * 7 + dw] + smax[sp] * saw[49 + dh * 7 + dw];
      }
    }
    sa[t] = sigf(acc);
  }
  __syncthreads();
  for (int s = w * 28; s < w * 28 + 28; ++s) {
    float sg = sa[s];
#pragma unroll
    for (int c = 0; c < 4; ++c) {
      int ch = lane + 64 * c;
      Dcat[(size_t)n * 159744 + ch * 624 + 512 + s] *= sg;
    }
  }
}

// Dict [256][512] + Dcat_f sd-part -> Db [n][2pl][256][640], DbT [n][2pl][640][256]
__global__ void dcatconv_k(const float* __restrict__ Dict, const float* __restrict__ Dc,
                           bf16* __restrict__ Db, bf16* __restrict__ DbT) {
  int idx = blockIdx.x * 256 + threadIdx.x;   // 2*256*640
  if (idx >= 327680) return;
  int n = idx / 163840, r = idx - n * 163840;
  int p = r / 640, a = r - p * 640;
  float v = 0.0f;
  if (a < 512)      v = Dict[p * 512 + a];
  else if (a < 624) v = Dc[(size_t)n * 159744 + p * 624 + a];
  bf16 h, l; split2(v, h, l);
  size_t base = (size_t)n * 327680;
  Db[base + p * 640 + a] = h;
  Db[base + 163840 + p * 640 + a] = l;
  DbT[base + (size_t)a * 256 + p] = h;
  DbT[base + 163840 + (size_t)a * 256 + p] = l;
}

// unfold for both batches into the stacked chunk buffer
__global__ void unfold_k(const float* __restrict__ img, bf16* __restrict__ uf,
                         int r0, int Rc, int bRowc, size_t pOff) {
  int bi = blockIdx.x;               // 0..2*Rc-1
  int nb = bi >= Rc;
  int rl = nb ? bi - Rc : bi;
  int row = nb * bRowc + rl;
  int p = threadIdx.x;
  int l = r0 + rl;
  int i0 = l / 113, j0 = l - i0 * 113;
  float v = img[nb * 16384 + (i0 + (p >> 4)) * 128 + j0 + (p & 15)];
  bf16 h, lo; split2(v, h, lo);
  size_t o = (size_t)row * 256 + p;
  uf[o] = h; uf[o + pOff] = lo;
}

// overlap-add fold + divide; 8 lanes per pixel (kh split), shfl reduce
__global__ void folddiv_k(const float* __restrict__ xpT, const float* __restrict__ wgT,
                          float* __restrict__ out) {
  int idx = blockIdx.x * 256 + threadIdx.x;  // 262144 = 32768 pixels * 8
  if (idx >= 262144) return;
  int g = idx & 7;
  int pix = idx >> 3;
  int n = pix >> 14, rem = pix & 16383;
  int i = rem >> 7, j = rem & 127;
  float num = 0.0f, den = 0.0f;
  int kh0 = (i - 112 > 0) ? i - 112 : 0;
  int kh1 = (i < 15) ? i : 15;
  int kw0 = (j - 112 > 0) ? j - 112 : 0;
  int kw1 = (j < 15) ? j : 15;
  for (int kh = kh0 + ((g - kh0) & 7); kh <= kh1; kh += 8)
    for (int kw = kw0; kw <= kw1; ++kw) {
      int l = (i - kh) * 113 + (j - kw);
      size_t base = (size_t)(kh * 16 + kw) * NLR + (size_t)n * L_LOC + l;
      num += xpT[base];
      den += wgT[base];
    }
#pragma unroll
  for (int o = 1; o < 8; o <<= 1) {
    num += __shfl_xor(num, o);
    den += __shfl_xor(den, o);
  }
  if (g == 0) out[pix] = num / den;
}

// ================= host orchestration ==========================================
struct Bufs {
  float *xp, *wg, *Dcat_f, *sd, *res;
  float *mv, *xv, *hm, *hx, *ca;
  bf16 *Db, *DbT, *Sb;
  bf16 *extb, *sdh1, *sdh2, *sdh3;
  bf16 *uf, *h1, *h2, *z, *zn, *thr, *y;
  size_t ufO, h2O;
  int R;
};

static void run_stage(hipStream_t st, const float* const* in, const float* img,
                      float* outimg, int pd0, int lam0,
                      bf16* const* WtPd, bf16* const* WtLam, bf16* const* WtW,
                      bf16* const* Ws, const Bufs& b)
{
  const float* cptr = in[2];
  const int BIG = 1 << 30;
  // --- adaptive dictionary pipeline via MFMA (TERMS=3 ~ fp32) ---
  extb_k<<<dim3(256), dim3(256), 0, st>>>(img, b.extb);
  mgemm(st, ME_RELU, 3, 1, b.extb, 256, 65536, Ws[0], Ws[0], 256, 512 * 256,
        b.sdh1, 512, 256 * 512, 0, in[4], 0, 0, 0, cptr, BIG, 224, 0, 256, 512, 256);
  mgemm(st, ME_RELU, 3, 1, b.sdh1, 512, 256 * 512, Ws[1], Ws[1], 512, 1024 * 512,
        b.sdh2, 1024, 256 * 1024, 0, in[6], 0, 0, 0, cptr, BIG, 224, 0, 256, 1024, 512);
  mgemm(st, ME_RELU, 3, 1, b.sdh2, 1024, 256 * 1024, Ws[2], Ws[2], 1024, 512 * 1024,
        b.sdh3, 512, 256 * 512, 0, in[8], 0, 0, 0, cptr, BIG, 224, 0, 256, 512, 1024);
  mgemm(st, ME_LIN, 3, 0, b.sdh3, 512, 256 * 512, Ws[3], Ws[3], 512, 256 * 512,
        b.sd, 256, 0, 0, in[10], 0, 0, 0, cptr, BIG, 224, 0, 256, 256, 512);
  rownorm224_k<<<dim3(224), dim3(64), 0, st>>>(b.sd);
  // CBAM, multi-block
  meanmax_k<<<dim3(2), dim3(256), 0, st>>>(b.sd, b.mv, b.xv);
  cah_k<<<dim3(4), dim3(256), 0, st>>>(b.mv, b.xv, in[41], b.hm, b.hx);
  cao_k<<<dim3(2), dim3(256), 0, st>>>(b.hm, b.hx, in[42], b.ca);
  spatial_k<<<dim3(2), dim3(256), 0, st>>>(b.sd, b.ca, in[43], b.Dcat_f);
  dcatconv_k<<<dim3(1280), dim3(256), 0, st>>>(in[1], b.Dcat_f, b.Db, b.DbT);
  // --- S = I - D^T D / c via split MFMA, fused split-bf16 output ---
  for (int n = 0; n < NB; ++n) {
    const bf16* Dt = b.DbT + (size_t)n * 327680;
    mgemm(st, ME_SMAT, 3, 0, Dt, 256, 163840, Dt, Dt, 256, 163840,
          b.Sb + (size_t)n * 819200, 640, 409600, 0,
          0, 0, 0, 0, cptr, BIG, 624, 0, 640, 640, 256);
  }

  // --- stacked both-batch chunks ---
  for (int r0 = 0; r0 < L_LOC; r0 += b.R) {
    int Rc = L_LOC - r0; if (Rc > b.R) Rc = b.R;
    int bRowc = ((Rc + 127) / 128) * 128;
    int Mp = 2 * bRowc;
    unfold_k<<<dim3(2 * Rc), dim3(256), 0, st>>>(img, b.uf, r0, Rc, bRowc, b.ufO);
    // pd MLP -> thr[:, :512]
    mgemm(st, ME_RELU, 1, 0, b.uf, 256, b.ufO, WtPd[0], WtPd[0], 256, 1024 * 256,
          b.h1, 1024, 0, 0, in[pd0 + 1], 0, 0, 0, cptr, bRowc, Rc, r0, Mp, 1024, 256);
    mgemm(st, ME_RELU, 1, 1, b.h1, 1024, 0, WtPd[1], WtPd[1], 1024, 512 * 1024,
          b.h2, 512, b.h2O, 0, in[pd0 + 3], 0, 0, 0, cptr, bRowc, Rc, r0, Mp, 512, 1024);
    mgemm(st, ME_SCALE, 3, 0, b.h2, 512, b.h2O, WtPd[2], WtPd[2], 512, 512 * 512,
          b.thr, 640, 0, 0, in[pd0 + 5], 0, 0, 0, cptr, bRowc, Rc, r0, Mp, 512, 512);
    // lam MLP -> thr[:, 512:624]
    mgemm(st, ME_RELU, 1, 0, b.uf, 256, b.ufO, WtLam[0], WtLam[0], 256, 1024 * 256,
          b.h1, 1024, 0, 0, in[lam0 + 1], 0, 0, 0, cptr, bRowc, Rc, r0, Mp, 1024, 256);
    mgemm(st, ME_RELU, 1, 1, b.h1, 1024, 0, WtLam[1], WtLam[1], 1024, 512 * 1024,
          b.h2, 512, b.h2O, 0, in[lam0 + 3], 0, 0, 0, cptr, bRowc, Rc, r0, Mp, 512, 1024);
    mgemm(st, ME_SCALE, 3, 0, b.h2, 512, b.h2O, WtLam[2], WtLam[2], 512, 128 * 512,
          b.thr + 512, 640, 0, 0, in[lam0 + 5], 0, 0, 0, cptr, bRowc, Rc, r0, Mp, 112, 512);
    // w MLP -> WgT (transposed, sigmoid)
    mgemm(st, ME_RELU, 1, 0, b.uf, 256, b.ufO, WtW[0], WtW[0], 256, 1024 * 256,
          b.h1, 1024, 0, 0, in[36], 0, 0, 0, cptr, bRowc, Rc, r0, Mp, 1024, 256);
    mgemm(st, ME_RELU, 1, 1, b.h1, 1024, 0, WtW[1], WtW[1], 1024, 512 * 1024,
          b.h2, 512, b.h2O, 0, in[38], 0, 0, 0, cptr, bRowc, Rc, r0, Mp, 512, 1024);
    mgemm(st, ME_SIG, 1, 0, b.h2, 512, b.h2O, WtW[2], WtW[2], 512, 256 * 512,
          b.wg, 0, 0, 0, in[40], 0, 0, 0, cptr, bRowc, Rc, r0, Mp, 256, 512);
    // y = uf @ Dcat (bf16 y), fused z0 = soft(y, thr)
    mgemm(st, ME_Y, 3, 0, b.uf, 256, b.ufO, b.DbT, b.DbT + 327680, 256, 163840,
          b.y, 640, 0, b.z, 0, b.thr, 0, 640, cptr, bRowc, Rc, r0, Mp, 624, 256);
    // LISTA iterations (z hi x S split, TERMS=2; y/thr bf16 epilogue)
    bf16* zi = b.z; bf16* zo = b.zn;
    for (int it = 0; it < 5; ++it) {
      mgemm(st, ME_SOFT, 2, 0, zi, 640, 0, b.Sb, b.Sb + 819200, 640, 409600,
            zo, 640, 0, 0, 0, b.y, b.thr, 640, cptr, bRowc, Rc, r0, Mp, 624, 640);
      bf16* tmp = zi; zi = zo; zo = tmp;
    }
    // x_pred -> xpT (transposed, clip * Wg), TERMS=2
    mgemm(st, ME_XP, 2, 0, zi, 640, 0, b.Db, b.Db + 327680, 640, 163840,
          b.xp, 0, 0, 0, 0, b.wg, 0, 0, cptr, bRowc, Rc, r0, Mp, 256, 640);
  }
  folddiv_k<<<dim3(1024), dim3(256), 0, st>>>(b.xp, b.wg, outimg);
}

extern "C" void kernel_launch(void* const* d_in, const int* in_sizes, int n_in,
                              void* d_out, int out_size, void* d_ws, size_t ws_size,
                              hipStream_t stream)
{
  (void)in_sizes; (void)n_in; (void)out_size;
  const float* const* in = (const float* const*)d_in;
  char* base = (char*)d_ws;
  size_t off = 0;
  auto allocf = [&](size_t nelem) -> float* {
    float* p = (float*)(base + off);
    off += ((nelem * 4 + 255) / 256) * 256;
    return p;
  };
  auto allocb2 = [&](size_t nelem) -> bf16* {  // hi+lo planes
    bf16* p = (bf16*)(base + off);
    off += ((nelem * 2 * 2 + 255) / 256) * 256;
    return p;
  };
  auto allocb1 = [&](size_t nelem) -> bf16* {  // single plane
    bf16* p = (bf16*)(base + off);
    off += ((nelem * 2 + 255) / 256) * 256;
    return p;
  };
  Bufs b;
  b.xp = allocf((size_t)NLR * 256);   // transposed [256][NLR]
  b.wg = allocf((size_t)NLR * 256);   // transposed [256][NLR]
  b.Dcat_f = allocf(2 * 256 * 624);
  b.sd = allocf(224 * 256);
  b.res = allocf(2 * 16384);
  b.mv = allocf(512); b.xv = allocf(512);
  b.hm = allocf(1024); b.hx = allocf(1024);
  b.ca = allocf(512);
  b.Db = allocb2(2 * 163840);
  b.DbT = allocb2(2 * 163840);
  b.Sb = allocb2(2 * 409600);
  b.extb = allocb2(256 * 256);
  b.sdh1 = allocb2(256 * 512);
  b.sdh2 = allocb2(256 * 1024);
  b.sdh3 = allocb2(256 * 512);

  // transposed split-bf16 weights (single merged launch)
  bf16 *Wa[3], *Wp[3], *Wb[3], *Wq[3], *Ww[3], *Ws[4];
  WTable wt;
  int ne = 0, tot = 0;
  auto addw = [&](const float* src, bf16* dst, int K, int N, int Kp, int Np) {
    wt.src[ne] = src; wt.dst[ne] = dst;
    wt.K[ne] = K; wt.N[ne] = N; wt.Kp[ne] = Kp; wt.Np[ne] = Np;
    wt.loOff[ne] = (long long)Np * Kp; wt.base[ne] = tot;
    tot += Np * Kp; ++ne;
  };
  int sdK[4] = {256, 512, 1024, 512}, sdN[4] = {512, 1024, 512, 256}, sdIdx[4] = {3, 5, 7, 9};
  for (int i = 0; i < 4; ++i) {
    Ws[i] = allocb2((size_t)sdN[i] * sdK[i]);
    addw(in[sdIdx[i]], Ws[i], sdK[i], sdN[i], sdK[i], sdN[i]);
  }
  struct WD { bf16** slot; int idx, K, N, Kp, Np; };
  WD wd[15] = {
    {&Wa[0], 11, 256, 1024, 256, 1024}, {&Wa[1], 13, 1024, 512, 1024, 512}, {&Wa[2], 15, 512, 112, 512, 128},
    {&Wp[0], 17, 256, 1024, 256, 1024}, {&Wp[1], 19, 1024, 512, 1024, 512}, {&Wp[2], 21, 512, 512, 512, 512},
    {&Wb[0], 23, 256, 1024, 256, 1024}, {&Wb[1], 25, 1024, 512, 1024, 512}, {&Wb[2], 27, 512, 112, 512, 128},
    {&Wq[0], 29, 256, 1024, 256, 1024}, {&Wq[1], 31, 1024, 512, 1024, 512}, {&Wq[2], 33, 512, 512, 512, 512},
    {&Ww[0], 35, 256, 1024, 256, 1024}, {&Ww[1], 37, 1024, 512, 1024, 512}, {&Ww[2], 39, 512, 256, 512, 256},
  };
  for (int i = 0; i < 15; ++i) {
    *wd[i].slot = allocb2((size_t)wd[i].Np * wd[i].Kp);
    addw(in[wd[i].idx], *wd[i].slot, wd[i].K, wd[i].N, wd[i].Kp, wd[i].Np);
  }
  wt.base[NW] = tot;
  wtransall_k<<<dim3((tot + 255) / 256), dim3(256), 0, stream>>>(wt);

  // chunk size (per batch-row bytes: uf 1024 + h1 2048 + h2 2048 + z 1280 +
  // zn 1280 + thr(bf16) 1280 + y(bf16) 1280 = 10240; chunk holds 2R rows)
  long long avail = (long long)ws_size - (long long)off - (1 << 20);
  long long perrow2 = 2LL * (10240 + 64);
  int R = 12800;
  if (avail / perrow2 < 12800) R = (int)(avail / perrow2);
  R &= ~127;
  if (R < 128) R = 128;
  b.R = R;
  size_t rows2 = (size_t)2 * R;
  b.uf = allocb2(rows2 * 256);  b.ufO = rows2 * 256;
  b.h1 = allocb1(rows2 * 1024);                       // hi only, reused 3x
  b.h2 = allocb2(rows2 * 512);  b.h2O = rows2 * 512;  // hi+lo (L3 TERMS=3)
  b.z = allocb1(rows2 * 640);
  b.zn = allocb1(rows2 * 640);
  b.thr = allocb1(rows2 * 640);
  b.y = allocb1(rows2 * 640);

  // stage 1: pd = p*(17), lam = a*(11); stage 2: pd = q*(29), lam = b*(23)
  run_stage(stream, in, in[0], b.res, 17, 11, Wp, Wa, Ww, Ws, b);
  run_stage(stream, in, b.res, (float*)d_out, 29, 23, Wq, Wb, Ww, Ws, b);
}